// Round 10
// baseline (502.602 us; speedup 1.0000x reference)
//
#include <hip/hip_runtime.h>
#include <cfloat>
#include <climits>
#include <cmath>

constexpr int N_ = 100000;
constexpr int E_ = 800000;
constexpr int NBLK_ = (N_ + 255) / 256;  // 391

#define GLOAD16(gp, lp)                                                        \
    __builtin_amdgcn_global_load_lds(                                          \
        (const __attribute__((address_space(1))) void*)(gp),                   \
        (__attribute__((address_space(3))) void*)(lp), 16, 0, 0)

// ---------------- time encoding + count init + per-block t min/max ----------------
__global__ __launch_bounds__(256) void k_prep(const int* __restrict__ ts, float* __restrict__ te,
                                              int* __restrict__ count, int* __restrict__ bmin,
                                              int* __restrict__ bmax) {
    const float FRQ[8] = {1.0f, 0.31622776601683794f, 0.1f, 0.031622776601683794f,
                          0.01f, 0.0031622776601683794f, 0.001f, 0.00031622776601683794f};
    int n = blockIdx.x * 256 + threadIdx.x;
    int tv_min = INT_MAX, tv_max = INT_MIN;
    if (n < N_) {
        int tv = ts[n];
        tv_min = tv; tv_max = tv;
        count[n] = 1;  // self loop
        float tf = (float)tv;
#pragma unroll
        for (int j = 0; j < 8; ++j) {
            float sv, cv;
            sincosf(tf * FRQ[j], &sv, &cv);
            te[n * 16 + j] = sv;
            te[n * 16 + 8 + j] = cv;
        }
    }
#pragma unroll
    for (int o = 32; o >= 1; o >>= 1) {
        tv_min = min(tv_min, __shfl_xor(tv_min, o));
        tv_max = max(tv_max, __shfl_xor(tv_max, o));
    }
    __shared__ int smn[4], smx[4];
    if ((threadIdx.x & 63) == 0) {
        smn[threadIdx.x >> 6] = tv_min;
        smx[threadIdx.x >> 6] = tv_max;
    }
    __syncthreads();
    if (threadIdx.x == 0) {
        bmin[blockIdx.x] = min(min(smn[0], smn[1]), min(smn[2], smn[3]));
        bmax[blockIdx.x] = max(max(smx[0], smx[1]), max(smx[2], smx[3]));
    }
}

__global__ __launch_bounds__(256) void k_count(const int* __restrict__ ei, int* __restrict__ count) {
    int e = blockIdx.x * 256 + threadIdx.x;
    if (e < E_) atomicAdd(&count[ei[E_ + e]], 1);
}

// ---- multi-block exclusive scan of count[N] ----
__global__ __launch_bounds__(256) void k_bsum(const int* __restrict__ count, int* __restrict__ bsum) {
    int i = blockIdx.x * 256 + threadIdx.x;
    int v = (i < N_) ? count[i] : 0;
#pragma unroll
    for (int o = 32; o >= 1; o >>= 1) v += __shfl_xor(v, o);
    __shared__ int wsum[4];
    if ((threadIdx.x & 63) == 0) wsum[threadIdx.x >> 6] = v;
    __syncthreads();
    if (threadIdx.x == 0) bsum[blockIdx.x] = wsum[0] + wsum[1] + wsum[2] + wsum[3];
}

__global__ __launch_bounds__(512) void k_bscan(int* __restrict__ bsum, int* __restrict__ indptr,
                                               const int* __restrict__ bmin, const int* __restrict__ bmax,
                                               int* __restrict__ minmax) {
    int t = threadIdx.x;
    int v = (t < NBLK_) ? bsum[t] : 0;
    __shared__ int sc[512];
    sc[t] = v;
    __syncthreads();
    for (int o = 1; o < 512; o <<= 1) {
        int u = (t >= o) ? sc[t - o] : 0;
        __syncthreads();
        sc[t] += u;
        __syncthreads();
    }
    if (t < NBLK_) bsum[t] = sc[t] - v;  // exclusive
    if (t == NBLK_ - 1) indptr[N_] = sc[t];
    // min/max reduce
    int mn = (t < NBLK_) ? bmin[t] : INT_MAX;
    int mx = (t < NBLK_) ? bmax[t] : INT_MIN;
#pragma unroll
    for (int o = 32; o >= 1; o >>= 1) {
        mn = min(mn, __shfl_xor(mn, o));
        mx = max(mx, __shfl_xor(mx, o));
    }
    __shared__ int rmn[8], rmx[8];
    if ((t & 63) == 0) { rmn[t >> 6] = mn; rmx[t >> 6] = mx; }
    __syncthreads();
    if (t == 0) {
        int a = INT_MAX, b = INT_MIN;
#pragma unroll
        for (int q = 0; q < 8; ++q) { a = min(a, rmn[q]); b = max(b, rmx[q]); }
        minmax[0] = a;
        minmax[1] = b;
    }
}

// intra-block scan + self-loop scatter + cursor init + (fused) gate MLP
__global__ __launch_bounds__(256) void k_scan_c(const int* __restrict__ count, const int* __restrict__ bsum,
                                                int* __restrict__ indptr, int* __restrict__ srcs,
                                                int* __restrict__ cursor, const int* __restrict__ ts,
                                                const int* __restrict__ minmax, const float* __restrict__ gw1,
                                                const float* __restrict__ gb1, const float* __restrict__ gw2,
                                                const float* __restrict__ gb2, float* __restrict__ gate) {
    int t = threadIdx.x;
    int i = blockIdx.x * 256 + t;
    int v = (i < N_) ? count[i] : 0;
    __shared__ int sc[256];
    sc[t] = v;
    __syncthreads();
    for (int o = 1; o < 256; o <<= 1) {
        int u = (t >= o) ? sc[t - o] : 0;
        __syncthreads();
        sc[t] += u;
        __syncthreads();
    }
    if (i < N_) {
        int off = bsum[blockIdx.x] + sc[t] - v;
        indptr[i] = off;
        srcs[off] = i;        // self loop first
        cursor[i] = off + 1;
        // gate
        float mn = (float)minmax[0], mx = (float)minmax[1];
        float age = ((float)ts[i] - mn) / fmaxf(mx - mn, 1.0f);
        float o2 = gb2[0];
#pragma unroll
        for (int j = 0; j < 16; ++j) {
            float hj = fmaxf(age * gw1[j] + gb1[j], 0.f);
            o2 += hj * gw2[j];
        }
        gate[i] = 1.f / (1.f + __expf(-o2));
    }
}

__global__ __launch_bounds__(256) void k_scatter(const int* __restrict__ ei, int* __restrict__ cursor,
                                                 int* __restrict__ srcs) {
    int e = blockIdx.x * 256 + threadIdx.x;
    if (e < E_) {
        int s = ei[e];
        int d = ei[E_ + e];
        int p = atomicAdd(&cursor[d], 1);
        srcs[p] = s;
    }
}

// ---- global->LDS direct staging of one K-chunk (A tile [row][KC] flat, W tile [kk][M] flat)
// LDS dest is wave-uniform base + lane*16 (hardware rule); global src is per-lane.
template <int K, int M, int KC, int MODE>
__device__ __forceinline__ void stage_tile(const float* __restrict__ A, const float* __restrict__ te,
                                           const float* __restrict__ W, float* as_buf, float* ws_buf,
                                           int r0, int k0, int wave, int lane) {
    constexpr int TB = (M / 4) * 16;
    constexpr int NWAVE = TB / 64;
    constexpr int ROWB = KC * 4;               // bytes per A row in tile
    constexpr int ASEG = (128 * ROWB) / 1024;  // 1KB segments in A tile
    constexpr int RPS = 1024 / ROWB;           // A rows per segment
    constexpr int LPR = ROWB / 16;             // lanes per A row
    constexpr int WROWB = M * 4;
    constexpr int WSEG = (KC * WROWB) / 1024;
    constexpr int WRPS = 1024 / WROWB;
    constexpr int WLPR = WROWB / 16;
    for (int j = wave; j < ASEG; j += NWAVE) {
        int row = j * RPS + lane / LPR;
        int gr = r0 + row;
        if (gr > N_ - 1) gr = N_ - 1;          // clamp: OOB rows never stored
        int c4 = lane % LPR;
        const float* gp;
        if (MODE == 0) {
            if (k0 < 128) gp = &A[gr * 128 + k0 + c4 * 4];
            else          gp = &te[gr * 16 + c4 * 4];
        } else {
            gp = &A[gr * K + k0 + c4 * 4];
        }
        GLOAD16(gp, as_buf + j * 256);
    }
    for (int j = wave; j < WSEG; j += NWAVE) {
        int kk = j * WRPS + lane / WLPR;
        int c4 = lane % WLPR;
        GLOAD16(&W[(k0 + kk) * M + c4 * 4], ws_buf + j * 256);
    }
}

// ---------------- fused fp32 GEMM, 128-row x M-col tile, 8x4 per-thread ----------------
// Double-buffered LDS + global_load_lds direct staging (m97 structure): loads for
// chunk c+1 are issued before chunk c's FMA block; the compiler's vmcnt(0) drain
// before the single per-chunk barrier finds them already landed.
// MODE 0: proj (A=x concat te, +bias, relu)           -> Cout = h
// MODE 1: conv (raw) + attention-logit epilogue       -> Cout = h2, al_s, al_d
// MODE 2: head (+bias, relu, fused @w2+b2)            -> Cout = out (N,2)
template <int K, int M, int KC, int MODE>
__global__ __launch_bounds__((M / 4) * 16) void k_gemm(const float* __restrict__ A, const float* __restrict__ te,
                                                       const float* __restrict__ W, const float* __restrict__ bias,
                                                       const float* __restrict__ asrc, const float* __restrict__ adst,
                                                       const float* __restrict__ w2, const float* __restrict__ b2,
                                                       float* __restrict__ Cout, float* __restrict__ al_s,
                                                       float* __restrict__ al_d) {
    constexpr int GR = 128;
    constexpr int CTH = M / 4;
    constexpr int NCH = K / KC;
    static_assert(K % KC == 0, "K%KC");
    __shared__ __align__(16) float As[2][GR * KC];   // flat [row][kc]
    __shared__ __align__(16) float Ws[2][KC * M];    // flat [kk][col]
    __shared__ float asl[128], adl[128];
    __shared__ float w2l[128];
    const int r0 = blockIdx.x * GR;
    const int tid = threadIdx.x;
    const int tx = tid % CTH, ty = tid / CTH;
    const int wave = tid >> 6, lane = tid & 63;
    if (MODE == 1 && tid < 128) { asl[tid] = asrc[tid]; adl[tid] = adst[tid]; }
    if (MODE == 2 && tid < 128) { w2l[tid] = w2[tid]; }
    float acc[8][4];
#pragma unroll
    for (int i = 0; i < 8; ++i)
#pragma unroll
        for (int j = 0; j < 4; ++j) acc[i][j] = 0.f;

    stage_tile<K, M, KC, MODE>(A, te, W, As[0], Ws[0], r0, 0, wave, lane);
    __syncthreads();
    for (int c = 0; c < NCH; ++c) {
        const int b = c & 1;
        if (c + 1 < NCH)
            stage_tile<K, M, KC, MODE>(A, te, W, As[b ^ 1], Ws[b ^ 1], r0, (c + 1) * KC, wave, lane);
#pragma unroll
        for (int q = 0; q < KC / 4; ++q) {
            float4 ar[8];
#pragma unroll
            for (int i = 0; i < 8; ++i)
                ar[i] = *(const float4*)&As[b][(ty * 8 + i) * KC + q * 4];
#pragma unroll
            for (int k2 = 0; k2 < 4; ++k2) {
                float4 w = *(const float4*)&Ws[b][(q * 4 + k2) * M + tx * 4];
                float wv[4] = {w.x, w.y, w.z, w.w};
#pragma unroll
                for (int i = 0; i < 8; ++i) {
                    const float* arp = (const float*)&ar[i];
                    float av = arp[k2];
#pragma unroll
                    for (int j = 0; j < 4; ++j) acc[i][j] = fmaf(av, wv[j], acc[i][j]);
                }
            }
        }
        __syncthreads();
    }

#pragma unroll
    for (int i = 0; i < 8; ++i) {
        int gr = r0 + ty * 8 + i;
        bool valid = gr < N_;
        if (MODE == 0) {
            if (valid) {
                float4 v;
                v.x = fmaxf(acc[i][0] + bias[tx * 4 + 0], 0.f);
                v.y = fmaxf(acc[i][1] + bias[tx * 4 + 1], 0.f);
                v.z = fmaxf(acc[i][2] + bias[tx * 4 + 2], 0.f);
                v.w = fmaxf(acc[i][3] + bias[tx * 4 + 3], 0.f);
                *(float4*)&Cout[gr * M + tx * 4] = v;
            }
        } else if (MODE == 1) {
            if (valid) {
                float4 v = make_float4(acc[i][0], acc[i][1], acc[i][2], acc[i][3]);
                *(float4*)&Cout[gr * M + tx * 4] = v;
            }
            float ps = 0.f, pd = 0.f;
#pragma unroll
            for (int q = 0; q < 4; ++q) {
                int c = tx * 4 + q;
                ps = fmaf(acc[i][q], asl[c], ps);
                pd = fmaf(acc[i][q], adl[c], pd);
            }
#pragma unroll
            for (int o = 1; o <= 4; o <<= 1) {
                ps += __shfl_xor(ps, o);
                pd += __shfl_xor(pd, o);
            }
            if (valid && (tx & 7) == 0) {
                int head = tx >> 3;
                al_s[gr * 4 + head] = ps;
                al_d[gr * 4 + head] = pd;
            }
        } else {
            float ps0 = 0.f, ps1 = 0.f;
#pragma unroll
            for (int q = 0; q < 4; ++q) {
                float hv = fmaxf(acc[i][q] + bias[tx * 4 + q], 0.f);
                int c = tx * 4 + q;
                ps0 = fmaf(hv, w2l[c * 2 + 0], ps0);
                ps1 = fmaf(hv, w2l[c * 2 + 1], ps1);
            }
#pragma unroll
            for (int o = 1; o <= 8; o <<= 1) {
                ps0 += __shfl_xor(ps0, o);
                ps1 += __shfl_xor(ps1, o);
            }
            if (valid && tx == 0) {
                *(float2*)&Cout[gr * 2] = make_float2(ps0 + b2[0], ps1 + b2[1]);
            }
        }
    }
}

// ---------------- GAT aggregation: 16-lane group per node, barrier-free ----------------
// Proven config (round 6/9): VGPR 36, occ ~64%, 2-edge unroll.
__global__ __launch_bounds__(256) void k_gat(const int* __restrict__ indptr, const int* __restrict__ srcs,
                                             const float* __restrict__ al_s, const float* __restrict__ al_d,
                                             const float* __restrict__ h2, const float* __restrict__ convb,
                                             const float* __restrict__ gamma, const float* __restrict__ beta,
                                             const float* __restrict__ mean, const float* __restrict__ var,
                                             const float* __restrict__ gate, float* __restrict__ hout) {
    int g = threadIdx.x >> 4, lg = threadIdx.x & 15;
    int n = blockIdx.x * 16 + g;
    if (n >= N_) return;
    int start = indptr[n], end = indptr[n + 1];
    int hl = lg >> 2;
    int c0 = lg * 8;
    float gn = gate[n];
    float4 ad4 = *(const float4*)&al_d[n * 4];
    float adv[4] = {ad4.x, ad4.y, ad4.z, ad4.w};
    float M[4] = {-FLT_MAX, -FLT_MAX, -FLT_MAX, -FLT_MAX};
    float D[4] = {0.f, 0.f, 0.f, 0.f};
    float ac[8] = {0.f, 0.f, 0.f, 0.f, 0.f, 0.f, 0.f, 0.f};

    for (int p0 = start; p0 < end; p0 += 16) {
        int cs = end - p0;
        if (cs > 16) cs = 16;
        float a[4];
        int s = 0;
        if (lg < cs) {
            s = srcs[p0 + lg];
            float4 as4 = *(const float4*)&al_s[s * 4];
            float asv[4] = {as4.x, as4.y, as4.z, as4.w};
#pragma unroll
            for (int h = 0; h < 4; ++h) {
                float x = asv[h] + adv[h];
                a[h] = x > 0.f ? x : 0.2f * x;
            }
        } else {
#pragma unroll
            for (int h = 0; h < 4; ++h) a[h] = -FLT_MAX;
        }
        float f[4], w[4];
#pragma unroll
        for (int h = 0; h < 4; ++h) {
            float m = a[h];
#pragma unroll
            for (int o = 8; o >= 1; o >>= 1) m = fmaxf(m, __shfl_xor(m, o));
            float Mn = fmaxf(M[h], m);
            f[h] = __expf(M[h] - Mn);
            M[h] = Mn;
            w[h] = __expf(a[h] - Mn);
            float sv = w[h];
#pragma unroll
            for (int o = 8; o >= 1; o >>= 1) sv += __shfl_xor(sv, o);
            D[h] = D[h] * f[h] + sv;
        }
        float fh = hl < 2 ? (hl == 0 ? f[0] : f[1]) : (hl == 2 ? f[2] : f[3]);
        float whl = hl < 2 ? (hl == 0 ? w[0] : w[1]) : (hl == 2 ? w[2] : w[3]);
#pragma unroll
        for (int q = 0; q < 8; ++q) ac[q] *= fh;
        int i = 0;
        for (; i + 1 < cs; i += 2) {
            float w0 = __shfl(whl, i, 16);
            float w1 = __shfl(whl, i + 1, 16);
            int s0 = __shfl(s, i, 16);
            int s1 = __shfl(s, i + 1, 16);
            float4 h0a = *(const float4*)&h2[s0 * 128 + c0];
            float4 h0b = *(const float4*)&h2[s0 * 128 + c0 + 4];
            float4 h1a = *(const float4*)&h2[s1 * 128 + c0];
            float4 h1b = *(const float4*)&h2[s1 * 128 + c0 + 4];
            ac[0] = fmaf(w0, h0a.x, ac[0]); ac[1] = fmaf(w0, h0a.y, ac[1]);
            ac[2] = fmaf(w0, h0a.z, ac[2]); ac[3] = fmaf(w0, h0a.w, ac[3]);
            ac[4] = fmaf(w0, h0b.x, ac[4]); ac[5] = fmaf(w0, h0b.y, ac[5]);
            ac[6] = fmaf(w0, h0b.z, ac[6]); ac[7] = fmaf(w0, h0b.w, ac[7]);
            ac[0] = fmaf(w1, h1a.x, ac[0]); ac[1] = fmaf(w1, h1a.y, ac[1]);
            ac[2] = fmaf(w1, h1a.z, ac[2]); ac[3] = fmaf(w1, h1a.w, ac[3]);
            ac[4] = fmaf(w1, h1b.x, ac[4]); ac[5] = fmaf(w1, h1b.y, ac[5]);
            ac[6] = fmaf(w1, h1b.z, ac[6]); ac[7] = fmaf(w1, h1b.w, ac[7]);
        }
        if (i < cs) {
            float w0 = __shfl(whl, i, 16);
            int s0 = __shfl(s, i, 16);
            float4 h0a = *(const float4*)&h2[s0 * 128 + c0];
            float4 h0b = *(const float4*)&h2[s0 * 128 + c0 + 4];
            ac[0] = fmaf(w0, h0a.x, ac[0]); ac[1] = fmaf(w0, h0a.y, ac[1]);
            ac[2] = fmaf(w0, h0a.z, ac[2]); ac[3] = fmaf(w0, h0a.w, ac[3]);
            ac[4] = fmaf(w0, h0b.x, ac[4]); ac[5] = fmaf(w0, h0b.y, ac[5]);
            ac[6] = fmaf(w0, h0b.z, ac[6]); ac[7] = fmaf(w0, h0b.w, ac[7]);
        }
    }

    float Dh = hl < 2 ? (hl == 0 ? D[0] : D[1]) : (hl == 2 ? D[2] : D[3]);
    float rd = 1.0f / (Dh + 1e-16f);
    float out8[8];
#pragma unroll
    for (int half = 0; half < 2; ++half) {
        int cb0 = c0 + half * 4;
        float4 cb = *(const float4*)&convb[cb0];
        float4 gm = *(const float4*)&gamma[cb0];
        float4 bt = *(const float4*)&beta[cb0];
        float4 mu = *(const float4*)&mean[cb0];
        float4 vr = *(const float4*)&var[cb0];
        float cbv[4] = {cb.x, cb.y, cb.z, cb.w};
        float gmv[4] = {gm.x, gm.y, gm.z, gm.w};
        float btv[4] = {bt.x, bt.y, bt.z, bt.w};
        float muv[4] = {mu.x, mu.y, mu.z, mu.w};
        float vrv[4] = {vr.x, vr.y, vr.z, vr.w};
#pragma unroll
        for (int q = 0; q < 4; ++q) {
            float val = ac[half * 4 + q] * rd + cbv[q];
            float sc = gmv[q] * rsqrtf(vrv[q] + 1e-5f);
            val = (val - muv[q]) * sc + btv[q];
            val = val > 0.f ? val : expm1f(val);
            out8[half * 4 + q] = val * gn;
        }
    }
    *(float4*)&hout[n * 128 + c0] = make_float4(out8[0], out8[1], out8[2], out8[3]);
    *(float4*)&hout[n * 128 + c0 + 4] = make_float4(out8[4], out8[5], out8[6], out8[7]);
}

extern "C" void kernel_launch(void* const* d_in, const int* in_sizes, int n_in,
                              void* d_out, int out_size, void* d_ws, size_t ws_size,
                              hipStream_t stream) {
    const float* x       = (const float*)d_in[0];
    const int*   ei      = (const int*)d_in[1];
    const int*   ts      = (const int*)d_in[2];
    const float* proj_w  = (const float*)d_in[3];
    const float* proj_b  = (const float*)d_in[4];
    const float* conv_w  = (const float*)d_in[5];
    const float* conv_b  = (const float*)d_in[6];
    const float* att_src = (const float*)d_in[7];
    const float* att_dst = (const float*)d_in[8];
    const float* bn_g    = (const float*)d_in[9];
    const float* bn_b    = (const float*)d_in[10];
    const float* bn_m    = (const float*)d_in[11];
    const float* bn_v    = (const float*)d_in[12];
    const float* gw1     = (const float*)d_in[13];
    const float* gb1     = (const float*)d_in[14];
    const float* gw2     = (const float*)d_in[15];
    const float* gb2     = (const float*)d_in[16];
    const float* hw1     = (const float*)d_in[17];
    const float* hb1     = (const float*)d_in[18];
    const float* hw2     = (const float*)d_in[19];
    const float* hb2     = (const float*)d_in[20];
    float* out = (float*)d_out;

    float* ws   = (float*)d_ws;
    float* h    = ws;
    float* h2   = h + (size_t)N_ * 128;
    float* te   = h2 + (size_t)N_ * 128;
    float* al_s = te + (size_t)N_ * 16;
    float* al_d = al_s + (size_t)N_ * 4;
    float* gate = al_d + (size_t)N_ * 4;
    int* indptr = (int*)(gate + N_);
    int* srcs   = indptr + (N_ + 1);
    int* count  = srcs + (N_ + E_);
    int* cursor = count + N_;
    int* bsum   = cursor + N_;
    int* bmin   = bsum + NBLK_;
    int* bmax   = bmin + NBLK_;
    int* minmax = bmax + NBLK_;

    k_prep<<<NBLK_, 256, 0, stream>>>(ts, te, count, bmin, bmax);
    k_count<<<(E_ + 255) / 256, 256, 0, stream>>>(ei, count);
    k_bsum<<<NBLK_, 256, 0, stream>>>(count, bsum);
    k_bscan<<<1, 512, 0, stream>>>(bsum, indptr, bmin, bmax, minmax);
    k_scan_c<<<NBLK_, 256, 0, stream>>>(count, bsum, indptr, srcs, cursor, ts, minmax,
                                        gw1, gb1, gw2, gb2, gate);
    k_scatter<<<(E_ + 255) / 256, 256, 0, stream>>>(ei, cursor, srcs);

    k_gemm<144, 128, 16, 0><<<782, 512, 0, stream>>>(x, te, proj_w, proj_b, nullptr, nullptr,
                                                     nullptr, nullptr, h, nullptr, nullptr);
    for (int l = 0; l < 2; ++l) {
        k_gemm<128, 128, 32, 1><<<782, 512, 0, stream>>>(h, nullptr, conv_w + l * 128 * 128, nullptr,
                                                         att_src + l * 128, att_dst + l * 128,
                                                         nullptr, nullptr, h2, al_s, al_d);
        k_gat<<<(N_ + 15) / 16, 256, 0, stream>>>(indptr, srcs, al_s, al_d, h2, conv_b + l * 128,
                                                  bn_g + l * 128, bn_b + l * 128, bn_m + l * 128,
                                                  bn_v + l * 128, gate, h);
    }
    k_gemm<128, 64, 32, 2><<<782, 256, 0, stream>>>(h, nullptr, hw1, hb1, nullptr, nullptr,
                                                    hw2, hb2, out, nullptr, nullptr);
}

// Round 11
// 478.650 us; speedup vs baseline: 1.0500x; 1.0500x over previous
//
#include <hip/hip_runtime.h>
#include <cfloat>
#include <climits>
#include <cmath>

constexpr int N_ = 100000;
constexpr int E_ = 800000;
constexpr int NBLK_ = (N_ + 255) / 256;  // 391

// ---------------- time encoding + count init + per-block t min/max ----------------
__global__ __launch_bounds__(256) void k_prep(const int* __restrict__ ts, float* __restrict__ te,
                                              int* __restrict__ count, int* __restrict__ bmin,
                                              int* __restrict__ bmax) {
    const float FRQ[8] = {1.0f, 0.31622776601683794f, 0.1f, 0.031622776601683794f,
                          0.01f, 0.0031622776601683794f, 0.001f, 0.00031622776601683794f};
    int n = blockIdx.x * 256 + threadIdx.x;
    int tv_min = INT_MAX, tv_max = INT_MIN;
    if (n < N_) {
        int tv = ts[n];
        tv_min = tv; tv_max = tv;
        count[n] = 1;  // self loop
        float tf = (float)tv;
#pragma unroll
        for (int j = 0; j < 8; ++j) {
            float sv, cv;
            sincosf(tf * FRQ[j], &sv, &cv);
            te[n * 16 + j] = sv;
            te[n * 16 + 8 + j] = cv;
        }
    }
#pragma unroll
    for (int o = 32; o >= 1; o >>= 1) {
        tv_min = min(tv_min, __shfl_xor(tv_min, o));
        tv_max = max(tv_max, __shfl_xor(tv_max, o));
    }
    __shared__ int smn[4], smx[4];
    if ((threadIdx.x & 63) == 0) {
        smn[threadIdx.x >> 6] = tv_min;
        smx[threadIdx.x >> 6] = tv_max;
    }
    __syncthreads();
    if (threadIdx.x == 0) {
        bmin[blockIdx.x] = min(min(smn[0], smn[1]), min(smn[2], smn[3]));
        bmax[blockIdx.x] = max(max(smx[0], smx[1]), max(smx[2], smx[3]));
    }
}

__global__ __launch_bounds__(256) void k_count(const int* __restrict__ ei, int* __restrict__ count) {
    int e = blockIdx.x * 256 + threadIdx.x;
    if (e < E_) atomicAdd(&count[ei[E_ + e]], 1);
}

// ---- multi-block exclusive scan of count[N] ----
__global__ __launch_bounds__(256) void k_bsum(const int* __restrict__ count, int* __restrict__ bsum) {
    int i = blockIdx.x * 256 + threadIdx.x;
    int v = (i < N_) ? count[i] : 0;
#pragma unroll
    for (int o = 32; o >= 1; o >>= 1) v += __shfl_xor(v, o);
    __shared__ int wsum[4];
    if ((threadIdx.x & 63) == 0) wsum[threadIdx.x >> 6] = v;
    __syncthreads();
    if (threadIdx.x == 0) bsum[blockIdx.x] = wsum[0] + wsum[1] + wsum[2] + wsum[3];
}

__global__ __launch_bounds__(512) void k_bscan(int* __restrict__ bsum, int* __restrict__ indptr,
                                               const int* __restrict__ bmin, const int* __restrict__ bmax,
                                               int* __restrict__ minmax) {
    int t = threadIdx.x;
    int v = (t < NBLK_) ? bsum[t] : 0;
    __shared__ int sc[512];
    sc[t] = v;
    __syncthreads();
    for (int o = 1; o < 512; o <<= 1) {
        int u = (t >= o) ? sc[t - o] : 0;
        __syncthreads();
        sc[t] += u;
        __syncthreads();
    }
    if (t < NBLK_) bsum[t] = sc[t] - v;  // exclusive
    if (t == NBLK_ - 1) indptr[N_] = sc[t];
    // min/max reduce
    int mn = (t < NBLK_) ? bmin[t] : INT_MAX;
    int mx = (t < NBLK_) ? bmax[t] : INT_MIN;
#pragma unroll
    for (int o = 32; o >= 1; o >>= 1) {
        mn = min(mn, __shfl_xor(mn, o));
        mx = max(mx, __shfl_xor(mx, o));
    }
    __shared__ int rmn[8], rmx[8];
    if ((t & 63) == 0) { rmn[t >> 6] = mn; rmx[t >> 6] = mx; }
    __syncthreads();
    if (t == 0) {
        int a = INT_MAX, b = INT_MIN;
#pragma unroll
        for (int q = 0; q < 8; ++q) { a = min(a, rmn[q]); b = max(b, rmx[q]); }
        minmax[0] = a;
        minmax[1] = b;
    }
}

// intra-block scan + self-loop scatter + cursor init + (fused) gate MLP
__global__ __launch_bounds__(256) void k_scan_c(const int* __restrict__ count, const int* __restrict__ bsum,
                                                int* __restrict__ indptr, int* __restrict__ srcs,
                                                int* __restrict__ cursor, const int* __restrict__ ts,
                                                const int* __restrict__ minmax, const float* __restrict__ gw1,
                                                const float* __restrict__ gb1, const float* __restrict__ gw2,
                                                const float* __restrict__ gb2, float* __restrict__ gate) {
    int t = threadIdx.x;
    int i = blockIdx.x * 256 + t;
    int v = (i < N_) ? count[i] : 0;
    __shared__ int sc[256];
    sc[t] = v;
    __syncthreads();
    for (int o = 1; o < 256; o <<= 1) {
        int u = (t >= o) ? sc[t - o] : 0;
        __syncthreads();
        sc[t] += u;
        __syncthreads();
    }
    if (i < N_) {
        int off = bsum[blockIdx.x] + sc[t] - v;
        indptr[i] = off;
        srcs[off] = i;        // self loop first
        cursor[i] = off + 1;
        // gate
        float mn = (float)minmax[0], mx = (float)minmax[1];
        float age = ((float)ts[i] - mn) / fmaxf(mx - mn, 1.0f);
        float o2 = gb2[0];
#pragma unroll
        for (int j = 0; j < 16; ++j) {
            float hj = fmaxf(age * gw1[j] + gb1[j], 0.f);
            o2 += hj * gw2[j];
        }
        gate[i] = 1.f / (1.f + __expf(-o2));
    }
}

__global__ __launch_bounds__(256) void k_scatter(const int* __restrict__ ei, int* __restrict__ cursor,
                                                 int* __restrict__ srcs) {
    int e = blockIdx.x * 256 + threadIdx.x;
    if (e < E_) {
        int s = ei[e];
        int d = ei[E_ + e];
        int p = atomicAdd(&cursor[d], 1);
        srcs[p] = s;
    }
}

// ---------------- fused fp32 GEMM, 128-row x M-col tile, 8x4 per-thread ----------------
// Block = (M/4) x 16 threads. acc = 32 regs. A tile in LDS (transposed staging);
// W read DIRECTLY from global in the FMA loop: each wave re-reads one 512B
// segment per kk -> L1-resident (W chunk 16KB << 32KB L1). This deletes the W
// LDS staging + halves LDS (~18KB -> 8 blocks/CU, wave-cap occupancy) so
// barrier/staging stalls of one block hide under FMAs of the other seven.
// W values & k-order identical -> bit-identical output.
// MODE 0: proj (A=x concat te, +bias, relu)           -> Cout = h
// MODE 1: conv (raw) + attention-logit epilogue       -> Cout = h2, al_s, al_d
// MODE 2: head (+bias, relu, fused @w2+b2)            -> Cout = out (N,2)
template <int K, int M, int KC, int MODE>
__global__ __launch_bounds__((M / 4) * 16) void k_gemm(const float* __restrict__ A, const float* __restrict__ te,
                                                       const float* __restrict__ W, const float* __restrict__ bias,
                                                       const float* __restrict__ asrc, const float* __restrict__ adst,
                                                       const float* __restrict__ w2, const float* __restrict__ b2,
                                                       float* __restrict__ Cout, float* __restrict__ al_s,
                                                       float* __restrict__ al_d) {
    constexpr int GR = 128;
    constexpr int CTH = M / 4;             // col-threads
    constexpr int TB = CTH * 16;           // block threads
    constexpr int NA = (GR * KC / 4) / TB; // A float4 loads per thread
    constexpr int F4R = KC / 4;            // float4 slots per A row
    static_assert(K % KC == 0, "K%KC");
    __shared__ float As[KC][GR + 4];
    __shared__ float asl[128], adl[128];
    __shared__ float w2l[128];
    const int r0 = blockIdx.x * GR;
    const int tid = threadIdx.x;
    const int tx = tid % CTH, ty = tid / CTH;
    if (MODE == 1 && tid < 128) { asl[tid] = asrc[tid]; adl[tid] = adst[tid]; }
    if (MODE == 2 && tid < 128) { w2l[tid] = w2[tid]; }
    float acc[8][4];
#pragma unroll
    for (int i = 0; i < 8; ++i)
#pragma unroll
        for (int j = 0; j < 4; ++j) acc[i][j] = 0.f;

    for (int k0 = 0; k0 < K; k0 += KC) {
        __syncthreads();
        // stage A tile: float4 coalesced loads, transposed scalar LDS writes
#pragma unroll
        for (int i = 0; i < NA; ++i) {
            int f = tid + i * TB;
            int row = f / F4R, fq = f % F4R;
            int gr = r0 + row;
            float4 v = make_float4(0.f, 0.f, 0.f, 0.f);
            if (gr < N_) {
                if (MODE == 0) {
                    int kg = k0 + fq * 4;
                    if (kg < 128) v = *(const float4*)&A[gr * 128 + kg];
                    else          v = *(const float4*)&te[gr * 16 + (kg - 128)];
                } else {
                    v = *(const float4*)&A[gr * K + k0 + fq * 4];
                }
            }
            As[fq * 4 + 0][row] = v.x;
            As[fq * 4 + 1][row] = v.y;
            As[fq * 4 + 2][row] = v.z;
            As[fq * 4 + 3][row] = v.w;
        }
        __syncthreads();
#pragma unroll
        for (int kk = 0; kk < KC; ++kk) {
            float4 a0 = *(const float4*)&As[kk][ty * 8];
            float4 a1 = *(const float4*)&As[kk][ty * 8 + 4];
            float av[8] = {a0.x, a0.y, a0.z, a0.w, a1.x, a1.y, a1.z, a1.w};
            float4 w = *(const float4*)&W[(k0 + kk) * M + tx * 4];   // L1-resident
            float wv[4] = {w.x, w.y, w.z, w.w};
#pragma unroll
            for (int i = 0; i < 8; ++i)
#pragma unroll
                for (int j = 0; j < 4; ++j) acc[i][j] = fmaf(av[i], wv[j], acc[i][j]);
        }
    }

#pragma unroll
    for (int i = 0; i < 8; ++i) {
        int gr = r0 + ty * 8 + i;
        bool valid = gr < N_;
        if (MODE == 0) {
            if (valid) {
                float4 v;
                v.x = fmaxf(acc[i][0] + bias[tx * 4 + 0], 0.f);
                v.y = fmaxf(acc[i][1] + bias[tx * 4 + 1], 0.f);
                v.z = fmaxf(acc[i][2] + bias[tx * 4 + 2], 0.f);
                v.w = fmaxf(acc[i][3] + bias[tx * 4 + 3], 0.f);
                *(float4*)&Cout[gr * M + tx * 4] = v;
            }
        } else if (MODE == 1) {
            if (valid) {
                float4 v = make_float4(acc[i][0], acc[i][1], acc[i][2], acc[i][3]);
                *(float4*)&Cout[gr * M + tx * 4] = v;
            }
            float ps = 0.f, pd = 0.f;
#pragma unroll
            for (int q = 0; q < 4; ++q) {
                int c = tx * 4 + q;
                ps = fmaf(acc[i][q], asl[c], ps);
                pd = fmaf(acc[i][q], adl[c], pd);
            }
#pragma unroll
            for (int o = 1; o <= 4; o <<= 1) {
                ps += __shfl_xor(ps, o);
                pd += __shfl_xor(pd, o);
            }
            if (valid && (tx & 7) == 0) {
                int head = tx >> 3;
                al_s[gr * 4 + head] = ps;
                al_d[gr * 4 + head] = pd;
            }
        } else {
            float ps0 = 0.f, ps1 = 0.f;
#pragma unroll
            for (int q = 0; q < 4; ++q) {
                float hv = fmaxf(acc[i][q] + bias[tx * 4 + q], 0.f);
                int c = tx * 4 + q;
                ps0 = fmaf(hv, w2l[c * 2 + 0], ps0);
                ps1 = fmaf(hv, w2l[c * 2 + 1], ps1);
            }
#pragma unroll
            for (int o = 1; o <= 8; o <<= 1) {
                ps0 += __shfl_xor(ps0, o);
                ps1 += __shfl_xor(ps1, o);
            }
            if (valid && tx == 0) {
                *(float2*)&Cout[gr * 2] = make_float2(ps0 + b2[0], ps1 + b2[1]);
            }
        }
    }
}

// ---------------- GAT aggregation: 16-lane group per node, barrier-free ----------------
// Proven config (round 6/9): VGPR 36, occ ~64%, 2-edge unroll.
__global__ __launch_bounds__(256) void k_gat(const int* __restrict__ indptr, const int* __restrict__ srcs,
                                             const float* __restrict__ al_s, const float* __restrict__ al_d,
                                             const float* __restrict__ h2, const float* __restrict__ convb,
                                             const float* __restrict__ gamma, const float* __restrict__ beta,
                                             const float* __restrict__ mean, const float* __restrict__ var,
                                             const float* __restrict__ gate, float* __restrict__ hout) {
    int g = threadIdx.x >> 4, lg = threadIdx.x & 15;
    int n = blockIdx.x * 16 + g;
    if (n >= N_) return;
    int start = indptr[n], end = indptr[n + 1];
    int hl = lg >> 2;
    int c0 = lg * 8;
    float gn = gate[n];
    float4 ad4 = *(const float4*)&al_d[n * 4];
    float adv[4] = {ad4.x, ad4.y, ad4.z, ad4.w};
    float M[4] = {-FLT_MAX, -FLT_MAX, -FLT_MAX, -FLT_MAX};
    float D[4] = {0.f, 0.f, 0.f, 0.f};
    float ac[8] = {0.f, 0.f, 0.f, 0.f, 0.f, 0.f, 0.f, 0.f};

    for (int p0 = start; p0 < end; p0 += 16) {
        int cs = end - p0;
        if (cs > 16) cs = 16;
        float a[4];
        int s = 0;
        if (lg < cs) {
            s = srcs[p0 + lg];
            float4 as4 = *(const float4*)&al_s[s * 4];
            float asv[4] = {as4.x, as4.y, as4.z, as4.w};
#pragma unroll
            for (int h = 0; h < 4; ++h) {
                float x = asv[h] + adv[h];
                a[h] = x > 0.f ? x : 0.2f * x;
            }
        } else {
#pragma unroll
            for (int h = 0; h < 4; ++h) a[h] = -FLT_MAX;
        }
        float f[4], w[4];
#pragma unroll
        for (int h = 0; h < 4; ++h) {
            float m = a[h];
#pragma unroll
            for (int o = 8; o >= 1; o >>= 1) m = fmaxf(m, __shfl_xor(m, o));
            float Mn = fmaxf(M[h], m);
            f[h] = __expf(M[h] - Mn);
            M[h] = Mn;
            w[h] = __expf(a[h] - Mn);
            float sv = w[h];
#pragma unroll
            for (int o = 8; o >= 1; o >>= 1) sv += __shfl_xor(sv, o);
            D[h] = D[h] * f[h] + sv;
        }
        float fh = hl < 2 ? (hl == 0 ? f[0] : f[1]) : (hl == 2 ? f[2] : f[3]);
        float whl = hl < 2 ? (hl == 0 ? w[0] : w[1]) : (hl == 2 ? w[2] : w[3]);
#pragma unroll
        for (int q = 0; q < 8; ++q) ac[q] *= fh;
        int i = 0;
        for (; i + 1 < cs; i += 2) {
            float w0 = __shfl(whl, i, 16);
            float w1 = __shfl(whl, i + 1, 16);
            int s0 = __shfl(s, i, 16);
            int s1 = __shfl(s, i + 1, 16);
            float4 h0a = *(const float4*)&h2[s0 * 128 + c0];
            float4 h0b = *(const float4*)&h2[s0 * 128 + c0 + 4];
            float4 h1a = *(const float4*)&h2[s1 * 128 + c0];
            float4 h1b = *(const float4*)&h2[s1 * 128 + c0 + 4];
            ac[0] = fmaf(w0, h0a.x, ac[0]); ac[1] = fmaf(w0, h0a.y, ac[1]);
            ac[2] = fmaf(w0, h0a.z, ac[2]); ac[3] = fmaf(w0, h0a.w, ac[3]);
            ac[4] = fmaf(w0, h0b.x, ac[4]); ac[5] = fmaf(w0, h0b.y, ac[5]);
            ac[6] = fmaf(w0, h0b.z, ac[6]); ac[7] = fmaf(w0, h0b.w, ac[7]);
            ac[0] = fmaf(w1, h1a.x, ac[0]); ac[1] = fmaf(w1, h1a.y, ac[1]);
            ac[2] = fmaf(w1, h1a.z, ac[2]); ac[3] = fmaf(w1, h1a.w, ac[3]);
            ac[4] = fmaf(w1, h1b.x, ac[4]); ac[5] = fmaf(w1, h1b.y, ac[5]);
            ac[6] = fmaf(w1, h1b.z, ac[6]); ac[7] = fmaf(w1, h1b.w, ac[7]);
        }
        if (i < cs) {
            float w0 = __shfl(whl, i, 16);
            int s0 = __shfl(s, i, 16);
            float4 h0a = *(const float4*)&h2[s0 * 128 + c0];
            float4 h0b = *(const float4*)&h2[s0 * 128 + c0 + 4];
            ac[0] = fmaf(w0, h0a.x, ac[0]); ac[1] = fmaf(w0, h0a.y, ac[1]);
            ac[2] = fmaf(w0, h0a.z, ac[2]); ac[3] = fmaf(w0, h0a.w, ac[3]);
            ac[4] = fmaf(w0, h0b.x, ac[4]); ac[5] = fmaf(w0, h0b.y, ac[5]);
            ac[6] = fmaf(w0, h0b.z, ac[6]); ac[7] = fmaf(w0, h0b.w, ac[7]);
        }
    }

    float Dh = hl < 2 ? (hl == 0 ? D[0] : D[1]) : (hl == 2 ? D[2] : D[3]);
    float rd = 1.0f / (Dh + 1e-16f);
    float out8[8];
#pragma unroll
    for (int half = 0; half < 2; ++half) {
        int cb0 = c0 + half * 4;
        float4 cb = *(const float4*)&convb[cb0];
        float4 gm = *(const float4*)&gamma[cb0];
        float4 bt = *(const float4*)&beta[cb0];
        float4 mu = *(const float4*)&mean[cb0];
        float4 vr = *(const float4*)&var[cb0];
        float cbv[4] = {cb.x, cb.y, cb.z, cb.w};
        float gmv[4] = {gm.x, gm.y, gm.z, gm.w};
        float btv[4] = {bt.x, bt.y, bt.z, bt.w};
        float muv[4] = {mu.x, mu.y, mu.z, mu.w};
        float vrv[4] = {vr.x, vr.y, vr.z, vr.w};
#pragma unroll
        for (int q = 0; q < 4; ++q) {
            float val = ac[half * 4 + q] * rd + cbv[q];
            float sc = gmv[q] * rsqrtf(vrv[q] + 1e-5f);
            val = (val - muv[q]) * sc + btv[q];
            val = val > 0.f ? val : expm1f(val);
            out8[half * 4 + q] = val * gn;
        }
    }
    *(float4*)&hout[n * 128 + c0] = make_float4(out8[0], out8[1], out8[2], out8[3]);
    *(float4*)&hout[n * 128 + c0 + 4] = make_float4(out8[4], out8[5], out8[6], out8[7]);
}

extern "C" void kernel_launch(void* const* d_in, const int* in_sizes, int n_in,
                              void* d_out, int out_size, void* d_ws, size_t ws_size,
                              hipStream_t stream) {
    const float* x       = (const float*)d_in[0];
    const int*   ei      = (const int*)d_in[1];
    const int*   ts      = (const int*)d_in[2];
    const float* proj_w  = (const float*)d_in[3];
    const float* proj_b  = (const float*)d_in[4];
    const float* conv_w  = (const float*)d_in[5];
    const float* conv_b  = (const float*)d_in[6];
    const float* att_src = (const float*)d_in[7];
    const float* att_dst = (const float*)d_in[8];
    const float* bn_g    = (const float*)d_in[9];
    const float* bn_b    = (const float*)d_in[10];
    const float* bn_m    = (const float*)d_in[11];
    const float* bn_v    = (const float*)d_in[12];
    const float* gw1     = (const float*)d_in[13];
    const float* gb1     = (const float*)d_in[14];
    const float* gw2     = (const float*)d_in[15];
    const float* gb2     = (const float*)d_in[16];
    const float* hw1     = (const float*)d_in[17];
    const float* hb1     = (const float*)d_in[18];
    const float* hw2     = (const float*)d_in[19];
    const float* hb2     = (const float*)d_in[20];
    float* out = (float*)d_out;

    float* ws   = (float*)d_ws;
    float* h    = ws;
    float* h2   = h + (size_t)N_ * 128;
    float* te   = h2 + (size_t)N_ * 128;
    float* al_s = te + (size_t)N_ * 16;
    float* al_d = al_s + (size_t)N_ * 4;
    float* gate = al_d + (size_t)N_ * 4;
    int* indptr = (int*)(gate + N_);
    int* srcs   = indptr + (N_ + 1);
    int* count  = srcs + (N_ + E_);
    int* cursor = count + N_;
    int* bsum   = cursor + N_;
    int* bmin   = bsum + NBLK_;
    int* bmax   = bmin + NBLK_;
    int* minmax = bmax + NBLK_;

    k_prep<<<NBLK_, 256, 0, stream>>>(ts, te, count, bmin, bmax);
    k_count<<<(E_ + 255) / 256, 256, 0, stream>>>(ei, count);
    k_bsum<<<NBLK_, 256, 0, stream>>>(count, bsum);
    k_bscan<<<1, 512, 0, stream>>>(bsum, indptr, bmin, bmax, minmax);
    k_scan_c<<<NBLK_, 256, 0, stream>>>(count, bsum, indptr, srcs, cursor, ts, minmax,
                                        gw1, gb1, gw2, gb2, gate);
    k_scatter<<<(E_ + 255) / 256, 256, 0, stream>>>(ei, cursor, srcs);

    k_gemm<144, 128, 16, 0><<<782, 512, 0, stream>>>(x, te, proj_w, proj_b, nullptr, nullptr,
                                                     nullptr, nullptr, h, nullptr, nullptr);
    for (int l = 0; l < 2; ++l) {
        k_gemm<128, 128, 32, 1><<<782, 512, 0, stream>>>(h, nullptr, conv_w + l * 128 * 128, nullptr,
                                                         att_src + l * 128, att_dst + l * 128,
                                                         nullptr, nullptr, h2, al_s, al_d);
        k_gat<<<(N_ + 15) / 16, 256, 0, stream>>>(indptr, srcs, al_s, al_d, h2, conv_b + l * 128,
                                                  bn_g + l * 128, bn_b + l * 128, bn_m + l * 128,
                                                  bn_v + l * 128, gate, h);
    }
    k_gemm<128, 64, 32, 2><<<782, 256, 0, stream>>>(h, nullptr, hw1, hb1, nullptr, nullptr,
                                                    hw2, hb2, out, nullptr, nullptr);
}

// Round 12
// 465.348 us; speedup vs baseline: 1.0801x; 1.0286x over previous
//
#include <hip/hip_runtime.h>
#include <cfloat>
#include <climits>
#include <cmath>

constexpr int N_ = 100000;
constexpr int E_ = 800000;
constexpr int NBLK_ = (N_ + 255) / 256;  // 391

// ---------------- time encoding + count init + per-block t min/max ----------------
__global__ __launch_bounds__(256) void k_prep(const int* __restrict__ ts, float* __restrict__ te,
                                              int* __restrict__ count, int* __restrict__ bmin,
                                              int* __restrict__ bmax) {
    const float FRQ[8] = {1.0f, 0.31622776601683794f, 0.1f, 0.031622776601683794f,
                          0.01f, 0.0031622776601683794f, 0.001f, 0.00031622776601683794f};
    int n = blockIdx.x * 256 + threadIdx.x;
    int tv_min = INT_MAX, tv_max = INT_MIN;
    if (n < N_) {
        int tv = ts[n];
        tv_min = tv; tv_max = tv;
        count[n] = 1;  // self loop
        float tf = (float)tv;
#pragma unroll
        for (int j = 0; j < 8; ++j) {
            float sv, cv;
            sincosf(tf * FRQ[j], &sv, &cv);
            te[n * 16 + j] = sv;
            te[n * 16 + 8 + j] = cv;
        }
    }
#pragma unroll
    for (int o = 32; o >= 1; o >>= 1) {
        tv_min = min(tv_min, __shfl_xor(tv_min, o));
        tv_max = max(tv_max, __shfl_xor(tv_max, o));
    }
    __shared__ int smn[4], smx[4];
    if ((threadIdx.x & 63) == 0) {
        smn[threadIdx.x >> 6] = tv_min;
        smx[threadIdx.x >> 6] = tv_max;
    }
    __syncthreads();
    if (threadIdx.x == 0) {
        bmin[blockIdx.x] = min(min(smn[0], smn[1]), min(smn[2], smn[3]));
        bmax[blockIdx.x] = max(max(smx[0], smx[1]), max(smx[2], smx[3]));
    }
}

__global__ __launch_bounds__(256) void k_count(const int* __restrict__ ei, int* __restrict__ count) {
    int e = blockIdx.x * 256 + threadIdx.x;
    if (e < E_) atomicAdd(&count[ei[E_ + e]], 1);
}

// ---- multi-block exclusive scan of count[N] ----
__global__ __launch_bounds__(256) void k_bsum(const int* __restrict__ count, int* __restrict__ bsum) {
    int i = blockIdx.x * 256 + threadIdx.x;
    int v = (i < N_) ? count[i] : 0;
#pragma unroll
    for (int o = 32; o >= 1; o >>= 1) v += __shfl_xor(v, o);
    __shared__ int wsum[4];
    if ((threadIdx.x & 63) == 0) wsum[threadIdx.x >> 6] = v;
    __syncthreads();
    if (threadIdx.x == 0) bsum[blockIdx.x] = wsum[0] + wsum[1] + wsum[2] + wsum[3];
}

__global__ __launch_bounds__(512) void k_bscan(int* __restrict__ bsum, int* __restrict__ indptr,
                                               const int* __restrict__ bmin, const int* __restrict__ bmax,
                                               int* __restrict__ minmax) {
    int t = threadIdx.x;
    int v = (t < NBLK_) ? bsum[t] : 0;
    __shared__ int sc[512];
    sc[t] = v;
    __syncthreads();
    for (int o = 1; o < 512; o <<= 1) {
        int u = (t >= o) ? sc[t - o] : 0;
        __syncthreads();
        sc[t] += u;
        __syncthreads();
    }
    if (t < NBLK_) bsum[t] = sc[t] - v;  // exclusive
    if (t == NBLK_ - 1) indptr[N_] = sc[t];
    // min/max reduce
    int mn = (t < NBLK_) ? bmin[t] : INT_MAX;
    int mx = (t < NBLK_) ? bmax[t] : INT_MIN;
#pragma unroll
    for (int o = 32; o >= 1; o >>= 1) {
        mn = min(mn, __shfl_xor(mn, o));
        mx = max(mx, __shfl_xor(mx, o));
    }
    __shared__ int rmn[8], rmx[8];
    if ((t & 63) == 0) { rmn[t >> 6] = mn; rmx[t >> 6] = mx; }
    __syncthreads();
    if (t == 0) {
        int a = INT_MAX, b = INT_MIN;
#pragma unroll
        for (int q = 0; q < 8; ++q) { a = min(a, rmn[q]); b = max(b, rmx[q]); }
        minmax[0] = a;
        minmax[1] = b;
    }
}

// intra-block scan + self-loop scatter + cursor init + (fused) gate MLP
__global__ __launch_bounds__(256) void k_scan_c(const int* __restrict__ count, const int* __restrict__ bsum,
                                                int* __restrict__ indptr, int* __restrict__ srcs,
                                                int* __restrict__ cursor, const int* __restrict__ ts,
                                                const int* __restrict__ minmax, const float* __restrict__ gw1,
                                                const float* __restrict__ gb1, const float* __restrict__ gw2,
                                                const float* __restrict__ gb2, float* __restrict__ gate) {
    int t = threadIdx.x;
    int i = blockIdx.x * 256 + t;
    int v = (i < N_) ? count[i] : 0;
    __shared__ int sc[256];
    sc[t] = v;
    __syncthreads();
    for (int o = 1; o < 256; o <<= 1) {
        int u = (t >= o) ? sc[t - o] : 0;
        __syncthreads();
        sc[t] += u;
        __syncthreads();
    }
    if (i < N_) {
        int off = bsum[blockIdx.x] + sc[t] - v;
        indptr[i] = off;
        srcs[off] = i;        // self loop first
        cursor[i] = off + 1;
        // gate
        float mn = (float)minmax[0], mx = (float)minmax[1];
        float age = ((float)ts[i] - mn) / fmaxf(mx - mn, 1.0f);
        float o2 = gb2[0];
#pragma unroll
        for (int j = 0; j < 16; ++j) {
            float hj = fmaxf(age * gw1[j] + gb1[j], 0.f);
            o2 += hj * gw2[j];
        }
        gate[i] = 1.f / (1.f + __expf(-o2));
    }
}

__global__ __launch_bounds__(256) void k_scatter(const int* __restrict__ ei, int* __restrict__ cursor,
                                                 int* __restrict__ srcs) {
    int e = blockIdx.x * 256 + threadIdx.x;
    if (e < E_) {
        int s = ei[e];
        int d = ei[E_ + e];
        int p = atomicAdd(&cursor[d], 1);
        srcs[p] = s;
    }
}

// ---------------- fused fp32 GEMM, GR-row x M-col tile, 8x4 per-thread ----------------
// GR=64 -> grid ~1563 blocks (~6.1/CU): many independent barrier domains per CU,
// so one block's staging stall hides under other blocks' FMAs (the within-block
// pipelining attempts all failed; this buys the overlap across blocks instead).
// A tile in LDS (transposed staging, ~4.3KB); W read directly from global
// (L1/L2-resident, 512B/wave/kk broadcast). Inner loop & k-order identical to
// the proven round-6/8 kernel -> bit-identical output.
// MODE 0: proj (A=x concat te, +bias, relu)           -> Cout = h
// MODE 1: conv (raw) + attention-logit epilogue       -> Cout = h2, al_s, al_d
// MODE 2: head (+bias, relu, fused @w2+b2)            -> Cout = out (N,2)
template <int K, int M, int KC, int GR, int MODE>
__global__ __launch_bounds__((M / 4) * (GR / 8)) void k_gemm(const float* __restrict__ A, const float* __restrict__ te,
                                                             const float* __restrict__ W, const float* __restrict__ bias,
                                                             const float* __restrict__ asrc, const float* __restrict__ adst,
                                                             const float* __restrict__ w2, const float* __restrict__ b2,
                                                             float* __restrict__ Cout, float* __restrict__ al_s,
                                                             float* __restrict__ al_d) {
    constexpr int CTH = M / 4;             // col-threads
    constexpr int TB = CTH * (GR / 8);     // block threads
    constexpr int NA = (GR * KC / 4) / TB; // A float4 loads per thread
    constexpr int F4R = KC / 4;            // float4 slots per A row
    static_assert(K % KC == 0, "K%KC");
    static_assert(NA >= 1, "NA");
    __shared__ float As[KC][GR + 4];
    __shared__ float asl[128], adl[128];
    __shared__ float w2l[128];
    const int r0 = blockIdx.x * GR;
    const int tid = threadIdx.x;
    const int tx = tid % CTH, ty = tid / CTH;
    if (MODE == 1 && tid < 128) { asl[tid] = asrc[tid]; adl[tid] = adst[tid]; }
    if (MODE == 2 && tid < 128) { w2l[tid] = w2[tid]; }
    float acc[8][4];
#pragma unroll
    for (int i = 0; i < 8; ++i)
#pragma unroll
        for (int j = 0; j < 4; ++j) acc[i][j] = 0.f;

    for (int k0 = 0; k0 < K; k0 += KC) {
        __syncthreads();
        // stage A tile: float4 coalesced loads, transposed scalar LDS writes
#pragma unroll
        for (int i = 0; i < NA; ++i) {
            int f = tid + i * TB;
            int row = f / F4R, fq = f % F4R;
            int gr = r0 + row;
            float4 v = make_float4(0.f, 0.f, 0.f, 0.f);
            if (gr < N_) {
                if (MODE == 0) {
                    int kg = k0 + fq * 4;
                    if (kg < 128) v = *(const float4*)&A[gr * 128 + kg];
                    else          v = *(const float4*)&te[gr * 16 + (kg - 128)];
                } else {
                    v = *(const float4*)&A[gr * K + k0 + fq * 4];
                }
            }
            As[fq * 4 + 0][row] = v.x;
            As[fq * 4 + 1][row] = v.y;
            As[fq * 4 + 2][row] = v.z;
            As[fq * 4 + 3][row] = v.w;
        }
        __syncthreads();
#pragma unroll
        for (int kk = 0; kk < KC; ++kk) {
            float4 a0 = *(const float4*)&As[kk][ty * 8];
            float4 a1 = *(const float4*)&As[kk][ty * 8 + 4];
            float av[8] = {a0.x, a0.y, a0.z, a0.w, a1.x, a1.y, a1.z, a1.w};
            float4 w = *(const float4*)&W[(k0 + kk) * M + tx * 4];   // L1/L2-resident
            float wv[4] = {w.x, w.y, w.z, w.w};
#pragma unroll
            for (int i = 0; i < 8; ++i)
#pragma unroll
                for (int j = 0; j < 4; ++j) acc[i][j] = fmaf(av[i], wv[j], acc[i][j]);
        }
    }

#pragma unroll
    for (int i = 0; i < 8; ++i) {
        int gr = r0 + ty * 8 + i;
        bool valid = gr < N_;
        if (MODE == 0) {
            if (valid) {
                float4 v;
                v.x = fmaxf(acc[i][0] + bias[tx * 4 + 0], 0.f);
                v.y = fmaxf(acc[i][1] + bias[tx * 4 + 1], 0.f);
                v.z = fmaxf(acc[i][2] + bias[tx * 4 + 2], 0.f);
                v.w = fmaxf(acc[i][3] + bias[tx * 4 + 3], 0.f);
                *(float4*)&Cout[gr * M + tx * 4] = v;
            }
        } else if (MODE == 1) {
            if (valid) {
                float4 v = make_float4(acc[i][0], acc[i][1], acc[i][2], acc[i][3]);
                *(float4*)&Cout[gr * M + tx * 4] = v;
            }
            float ps = 0.f, pd = 0.f;
#pragma unroll
            for (int q = 0; q < 4; ++q) {
                int c = tx * 4 + q;
                ps = fmaf(acc[i][q], asl[c], ps);
                pd = fmaf(acc[i][q], adl[c], pd);
            }
#pragma unroll
            for (int o = 1; o <= 4; o <<= 1) {
                ps += __shfl_xor(ps, o);
                pd += __shfl_xor(pd, o);
            }
            if (valid && (tx & 7) == 0) {
                int head = tx >> 3;
                al_s[gr * 4 + head] = ps;
                al_d[gr * 4 + head] = pd;
            }
        } else {
            float ps0 = 0.f, ps1 = 0.f;
#pragma unroll
            for (int q = 0; q < 4; ++q) {
                float hv = fmaxf(acc[i][q] + bias[tx * 4 + q], 0.f);
                int c = tx * 4 + q;
                ps0 = fmaf(hv, w2l[c * 2 + 0], ps0);
                ps1 = fmaf(hv, w2l[c * 2 + 1], ps1);
            }
#pragma unroll
            for (int o = 1; o <= 8; o <<= 1) {
                ps0 += __shfl_xor(ps0, o);
                ps1 += __shfl_xor(ps1, o);
            }
            if (valid && tx == 0) {
                *(float2*)&Cout[gr * 2] = make_float2(ps0 + b2[0], ps1 + b2[1]);
            }
        }
    }
}

// ---------------- GAT aggregation: 16-lane group per node, barrier-free ----------------
// Proven config (round 6/9): VGPR 36, occ ~64%, 2-edge unroll.
__global__ __launch_bounds__(256) void k_gat(const int* __restrict__ indptr, const int* __restrict__ srcs,
                                             const float* __restrict__ al_s, const float* __restrict__ al_d,
                                             const float* __restrict__ h2, const float* __restrict__ convb,
                                             const float* __restrict__ gamma, const float* __restrict__ beta,
                                             const float* __restrict__ mean, const float* __restrict__ var,
                                             const float* __restrict__ gate, float* __restrict__ hout) {
    int g = threadIdx.x >> 4, lg = threadIdx.x & 15;
    int n = blockIdx.x * 16 + g;
    if (n >= N_) return;
    int start = indptr[n], end = indptr[n + 1];
    int hl = lg >> 2;
    int c0 = lg * 8;
    float gn = gate[n];
    float4 ad4 = *(const float4*)&al_d[n * 4];
    float adv[4] = {ad4.x, ad4.y, ad4.z, ad4.w};
    float M[4] = {-FLT_MAX, -FLT_MAX, -FLT_MAX, -FLT_MAX};
    float D[4] = {0.f, 0.f, 0.f, 0.f};
    float ac[8] = {0.f, 0.f, 0.f, 0.f, 0.f, 0.f, 0.f, 0.f};

    for (int p0 = start; p0 < end; p0 += 16) {
        int cs = end - p0;
        if (cs > 16) cs = 16;
        float a[4];
        int s = 0;
        if (lg < cs) {
            s = srcs[p0 + lg];
            float4 as4 = *(const float4*)&al_s[s * 4];
            float asv[4] = {as4.x, as4.y, as4.z, as4.w};
#pragma unroll
            for (int h = 0; h < 4; ++h) {
                float x = asv[h] + adv[h];
                a[h] = x > 0.f ? x : 0.2f * x;
            }
        } else {
#pragma unroll
            for (int h = 0; h < 4; ++h) a[h] = -FLT_MAX;
        }
        float f[4], w[4];
#pragma unroll
        for (int h = 0; h < 4; ++h) {
            float m = a[h];
#pragma unroll
            for (int o = 8; o >= 1; o >>= 1) m = fmaxf(m, __shfl_xor(m, o));
            float Mn = fmaxf(M[h], m);
            f[h] = __expf(M[h] - Mn);
            M[h] = Mn;
            w[h] = __expf(a[h] - Mn);
            float sv = w[h];
#pragma unroll
            for (int o = 8; o >= 1; o >>= 1) sv += __shfl_xor(sv, o);
            D[h] = D[h] * f[h] + sv;
        }
        float fh = hl < 2 ? (hl == 0 ? f[0] : f[1]) : (hl == 2 ? f[2] : f[3]);
        float whl = hl < 2 ? (hl == 0 ? w[0] : w[1]) : (hl == 2 ? w[2] : w[3]);
#pragma unroll
        for (int q = 0; q < 8; ++q) ac[q] *= fh;
        int i = 0;
        for (; i + 1 < cs; i += 2) {
            float w0 = __shfl(whl, i, 16);
            float w1 = __shfl(whl, i + 1, 16);
            int s0 = __shfl(s, i, 16);
            int s1 = __shfl(s, i + 1, 16);
            float4 h0a = *(const float4*)&h2[s0 * 128 + c0];
            float4 h0b = *(const float4*)&h2[s0 * 128 + c0 + 4];
            float4 h1a = *(const float4*)&h2[s1 * 128 + c0];
            float4 h1b = *(const float4*)&h2[s1 * 128 + c0 + 4];
            ac[0] = fmaf(w0, h0a.x, ac[0]); ac[1] = fmaf(w0, h0a.y, ac[1]);
            ac[2] = fmaf(w0, h0a.z, ac[2]); ac[3] = fmaf(w0, h0a.w, ac[3]);
            ac[4] = fmaf(w0, h0b.x, ac[4]); ac[5] = fmaf(w0, h0b.y, ac[5]);
            ac[6] = fmaf(w0, h0b.z, ac[6]); ac[7] = fmaf(w0, h0b.w, ac[7]);
            ac[0] = fmaf(w1, h1a.x, ac[0]); ac[1] = fmaf(w1, h1a.y, ac[1]);
            ac[2] = fmaf(w1, h1a.z, ac[2]); ac[3] = fmaf(w1, h1a.w, ac[3]);
            ac[4] = fmaf(w1, h1b.x, ac[4]); ac[5] = fmaf(w1, h1b.y, ac[5]);
            ac[6] = fmaf(w1, h1b.z, ac[6]); ac[7] = fmaf(w1, h1b.w, ac[7]);
        }
        if (i < cs) {
            float w0 = __shfl(whl, i, 16);
            int s0 = __shfl(s, i, 16);
            float4 h0a = *(const float4*)&h2[s0 * 128 + c0];
            float4 h0b = *(const float4*)&h2[s0 * 128 + c0 + 4];
            ac[0] = fmaf(w0, h0a.x, ac[0]); ac[1] = fmaf(w0, h0a.y, ac[1]);
            ac[2] = fmaf(w0, h0a.z, ac[2]); ac[3] = fmaf(w0, h0a.w, ac[3]);
            ac[4] = fmaf(w0, h0b.x, ac[4]); ac[5] = fmaf(w0, h0b.y, ac[5]);
            ac[6] = fmaf(w0, h0b.z, ac[6]); ac[7] = fmaf(w0, h0b.w, ac[7]);
        }
    }

    float Dh = hl < 2 ? (hl == 0 ? D[0] : D[1]) : (hl == 2 ? D[2] : D[3]);
    float rd = 1.0f / (Dh + 1e-16f);
    float out8[8];
#pragma unroll
    for (int half = 0; half < 2; ++half) {
        int cb0 = c0 + half * 4;
        float4 cb = *(const float4*)&convb[cb0];
        float4 gm = *(const float4*)&gamma[cb0];
        float4 bt = *(const float4*)&beta[cb0];
        float4 mu = *(const float4*)&mean[cb0];
        float4 vr = *(const float4*)&var[cb0];
        float cbv[4] = {cb.x, cb.y, cb.z, cb.w};
        float gmv[4] = {gm.x, gm.y, gm.z, gm.w};
        float btv[4] = {bt.x, bt.y, bt.z, bt.w};
        float muv[4] = {mu.x, mu.y, mu.z, mu.w};
        float vrv[4] = {vr.x, vr.y, vr.z, vr.w};
#pragma unroll
        for (int q = 0; q < 4; ++q) {
            float val = ac[half * 4 + q] * rd + cbv[q];
            float sc = gmv[q] * rsqrtf(vrv[q] + 1e-5f);
            val = (val - muv[q]) * sc + btv[q];
            val = val > 0.f ? val : expm1f(val);
            out8[half * 4 + q] = val * gn;
        }
    }
    *(float4*)&hout[n * 128 + c0] = make_float4(out8[0], out8[1], out8[2], out8[3]);
    *(float4*)&hout[n * 128 + c0 + 4] = make_float4(out8[4], out8[5], out8[6], out8[7]);
}

extern "C" void kernel_launch(void* const* d_in, const int* in_sizes, int n_in,
                              void* d_out, int out_size, void* d_ws, size_t ws_size,
                              hipStream_t stream) {
    const float* x       = (const float*)d_in[0];
    const int*   ei      = (const int*)d_in[1];
    const int*   ts      = (const int*)d_in[2];
    const float* proj_w  = (const float*)d_in[3];
    const float* proj_b  = (const float*)d_in[4];
    const float* conv_w  = (const float*)d_in[5];
    const float* conv_b  = (const float*)d_in[6];
    const float* att_src = (const float*)d_in[7];
    const float* att_dst = (const float*)d_in[8];
    const float* bn_g    = (const float*)d_in[9];
    const float* bn_b    = (const float*)d_in[10];
    const float* bn_m    = (const float*)d_in[11];
    const float* bn_v    = (const float*)d_in[12];
    const float* gw1     = (const float*)d_in[13];
    const float* gb1     = (const float*)d_in[14];
    const float* gw2     = (const float*)d_in[15];
    const float* gb2     = (const float*)d_in[16];
    const float* hw1     = (const float*)d_in[17];
    const float* hb1     = (const float*)d_in[18];
    const float* hw2     = (const float*)d_in[19];
    const float* hb2     = (const float*)d_in[20];
    float* out = (float*)d_out;

    float* ws   = (float*)d_ws;
    float* h    = ws;
    float* h2   = h + (size_t)N_ * 128;
    float* te   = h2 + (size_t)N_ * 128;
    float* al_s = te + (size_t)N_ * 16;
    float* al_d = al_s + (size_t)N_ * 4;
    float* gate = al_d + (size_t)N_ * 4;
    int* indptr = (int*)(gate + N_);
    int* srcs   = indptr + (N_ + 1);
    int* count  = srcs + (N_ + E_);
    int* cursor = count + N_;
    int* bsum   = cursor + N_;
    int* bmin   = bsum + NBLK_;
    int* bmax   = bmin + NBLK_;
    int* minmax = bmax + NBLK_;

    k_prep<<<NBLK_, 256, 0, stream>>>(ts, te, count, bmin, bmax);
    k_count<<<(E_ + 255) / 256, 256, 0, stream>>>(ei, count);
    k_bsum<<<NBLK_, 256, 0, stream>>>(count, bsum);
    k_bscan<<<1, 512, 0, stream>>>(bsum, indptr, bmin, bmax, minmax);
    k_scan_c<<<NBLK_, 256, 0, stream>>>(count, bsum, indptr, srcs, cursor, ts, minmax,
                                        gw1, gb1, gw2, gb2, gate);
    k_scatter<<<(E_ + 255) / 256, 256, 0, stream>>>(ei, cursor, srcs);

    constexpr int GB = (N_ + 63) / 64;  // 1563 blocks (GR=64)
    k_gemm<144, 128, 16, 64, 0><<<GB, 256, 0, stream>>>(x, te, proj_w, proj_b, nullptr, nullptr,
                                                        nullptr, nullptr, h, nullptr, nullptr);
    for (int l = 0; l < 2; ++l) {
        k_gemm<128, 128, 16, 64, 1><<<GB, 256, 0, stream>>>(h, nullptr, conv_w + l * 128 * 128, nullptr,
                                                            att_src + l * 128, att_dst + l * 128,
                                                            nullptr, nullptr, h2, al_s, al_d);
        k_gat<<<(N_ + 15) / 16, 256, 0, stream>>>(indptr, srcs, al_s, al_d, h2, conv_b + l * 128,
                                                  bn_g + l * 128, bn_b + l * 128, bn_m + l * 128,
                                                  bn_v + l * 128, gate, h);
    }
    k_gemm<128, 64, 16, 64, 2><<<GB, 128, 0, stream>>>(h, nullptr, hw1, hb1, nullptr, nullptr,
                                                       hw2, hb2, out, nullptr, nullptr);
}

// Round 13
// 465.042 us; speedup vs baseline: 1.0808x; 1.0007x over previous
//
#include <hip/hip_runtime.h>
#include <cfloat>
#include <climits>
#include <cmath>

constexpr int N_ = 100000;
constexpr int E_ = 800000;
constexpr int NBLK_ = (N_ + 255) / 256;  // 391

// ---------------- time encoding + count init + per-block t min/max ----------------
__global__ __launch_bounds__(256) void k_prep(const int* __restrict__ ts, float* __restrict__ te,
                                              int* __restrict__ count, int* __restrict__ bmin,
                                              int* __restrict__ bmax) {
    const float FRQ[8] = {1.0f, 0.31622776601683794f, 0.1f, 0.031622776601683794f,
                          0.01f, 0.0031622776601683794f, 0.001f, 0.00031622776601683794f};
    int n = blockIdx.x * 256 + threadIdx.x;
    int tv_min = INT_MAX, tv_max = INT_MIN;
    if (n < N_) {
        int tv = ts[n];
        tv_min = tv; tv_max = tv;
        count[n] = 1;  // self loop
        float tf = (float)tv;
#pragma unroll
        for (int j = 0; j < 8; ++j) {
            float sv, cv;
            sincosf(tf * FRQ[j], &sv, &cv);
            te[n * 16 + j] = sv;
            te[n * 16 + 8 + j] = cv;
        }
    }
#pragma unroll
    for (int o = 32; o >= 1; o >>= 1) {
        tv_min = min(tv_min, __shfl_xor(tv_min, o));
        tv_max = max(tv_max, __shfl_xor(tv_max, o));
    }
    __shared__ int smn[4], smx[4];
    if ((threadIdx.x & 63) == 0) {
        smn[threadIdx.x >> 6] = tv_min;
        smx[threadIdx.x >> 6] = tv_max;
    }
    __syncthreads();
    if (threadIdx.x == 0) {
        bmin[blockIdx.x] = min(min(smn[0], smn[1]), min(smn[2], smn[3]));
        bmax[blockIdx.x] = max(max(smx[0], smx[1]), max(smx[2], smx[3]));
    }
}

__global__ __launch_bounds__(256) void k_count(const int* __restrict__ ei, int* __restrict__ count) {
    int e = blockIdx.x * 256 + threadIdx.x;
    if (e < E_) atomicAdd(&count[ei[E_ + e]], 1);
}

// ---- multi-block exclusive scan of count[N] ----
__global__ __launch_bounds__(256) void k_bsum(const int* __restrict__ count, int* __restrict__ bsum) {
    int i = blockIdx.x * 256 + threadIdx.x;
    int v = (i < N_) ? count[i] : 0;
#pragma unroll
    for (int o = 32; o >= 1; o >>= 1) v += __shfl_xor(v, o);
    __shared__ int wsum[4];
    if ((threadIdx.x & 63) == 0) wsum[threadIdx.x >> 6] = v;
    __syncthreads();
    if (threadIdx.x == 0) bsum[blockIdx.x] = wsum[0] + wsum[1] + wsum[2] + wsum[3];
}

__global__ __launch_bounds__(512) void k_bscan(int* __restrict__ bsum, int* __restrict__ indptr,
                                               const int* __restrict__ bmin, const int* __restrict__ bmax,
                                               int* __restrict__ minmax) {
    int t = threadIdx.x;
    int v = (t < NBLK_) ? bsum[t] : 0;
    __shared__ int sc[512];
    sc[t] = v;
    __syncthreads();
    for (int o = 1; o < 512; o <<= 1) {
        int u = (t >= o) ? sc[t - o] : 0;
        __syncthreads();
        sc[t] += u;
        __syncthreads();
    }
    if (t < NBLK_) bsum[t] = sc[t] - v;  // exclusive
    if (t == NBLK_ - 1) indptr[N_] = sc[t];
    // min/max reduce
    int mn = (t < NBLK_) ? bmin[t] : INT_MAX;
    int mx = (t < NBLK_) ? bmax[t] : INT_MIN;
#pragma unroll
    for (int o = 32; o >= 1; o >>= 1) {
        mn = min(mn, __shfl_xor(mn, o));
        mx = max(mx, __shfl_xor(mx, o));
    }
    __shared__ int rmn[8], rmx[8];
    if ((t & 63) == 0) { rmn[t >> 6] = mn; rmx[t >> 6] = mx; }
    __syncthreads();
    if (t == 0) {
        int a = INT_MAX, b = INT_MIN;
#pragma unroll
        for (int q = 0; q < 8; ++q) { a = min(a, rmn[q]); b = max(b, rmx[q]); }
        minmax[0] = a;
        minmax[1] = b;
    }
}

// intra-block scan + self-loop scatter + cursor init + (fused) gate MLP
__global__ __launch_bounds__(256) void k_scan_c(const int* __restrict__ count, const int* __restrict__ bsum,
                                                int* __restrict__ indptr, int* __restrict__ srcs,
                                                int* __restrict__ cursor, const int* __restrict__ ts,
                                                const int* __restrict__ minmax, const float* __restrict__ gw1,
                                                const float* __restrict__ gb1, const float* __restrict__ gw2,
                                                const float* __restrict__ gb2, float* __restrict__ gate) {
    int t = threadIdx.x;
    int i = blockIdx.x * 256 + t;
    int v = (i < N_) ? count[i] : 0;
    __shared__ int sc[256];
    sc[t] = v;
    __syncthreads();
    for (int o = 1; o < 256; o <<= 1) {
        int u = (t >= o) ? sc[t - o] : 0;
        __syncthreads();
        sc[t] += u;
        __syncthreads();
    }
    if (i < N_) {
        int off = bsum[blockIdx.x] + sc[t] - v;
        indptr[i] = off;
        srcs[off] = i;        // self loop first
        cursor[i] = off + 1;
        // gate
        float mn = (float)minmax[0], mx = (float)minmax[1];
        float age = ((float)ts[i] - mn) / fmaxf(mx - mn, 1.0f);
        float o2 = gb2[0];
#pragma unroll
        for (int j = 0; j < 16; ++j) {
            float hj = fmaxf(age * gw1[j] + gb1[j], 0.f);
            o2 += hj * gw2[j];
        }
        gate[i] = 1.f / (1.f + __expf(-o2));
    }
}

__global__ __launch_bounds__(256) void k_scatter(const int* __restrict__ ei, int* __restrict__ cursor,
                                                 int* __restrict__ srcs) {
    int e = blockIdx.x * 256 + threadIdx.x;
    if (e < E_) {
        int s = ei[e];
        int d = ei[E_ + e];
        int p = atomicAdd(&cursor[d], 1);
        srcs[p] = s;
    }
}

// ---------------- fused fp32 GEMM, GR-row x M-col tile, 8x4 per-thread ----------------
// GR=64 -> ~1563 blocks (~6.1/CU). A tile in LDS; W direct from global (L1/L2).
// Proven round-12 config, bit-identical inner loop.
template <int K, int M, int KC, int GR, int MODE>
__global__ __launch_bounds__((M / 4) * (GR / 8)) void k_gemm(const float* __restrict__ A, const float* __restrict__ te,
                                                             const float* __restrict__ W, const float* __restrict__ bias,
                                                             const float* __restrict__ asrc, const float* __restrict__ adst,
                                                             const float* __restrict__ w2, const float* __restrict__ b2,
                                                             float* __restrict__ Cout, float* __restrict__ al_s,
                                                             float* __restrict__ al_d) {
    constexpr int CTH = M / 4;             // col-threads
    constexpr int TB = CTH * (GR / 8);     // block threads
    constexpr int NA = (GR * KC / 4) / TB; // A float4 loads per thread
    constexpr int F4R = KC / 4;            // float4 slots per A row
    static_assert(K % KC == 0, "K%KC");
    static_assert(NA >= 1, "NA");
    __shared__ float As[KC][GR + 4];
    __shared__ float asl[128], adl[128];
    __shared__ float w2l[128];
    const int r0 = blockIdx.x * GR;
    const int tid = threadIdx.x;
    const int tx = tid % CTH, ty = tid / CTH;
    if (MODE == 1 && tid < 128) { asl[tid] = asrc[tid]; adl[tid] = adst[tid]; }
    if (MODE == 2 && tid < 128) { w2l[tid] = w2[tid]; }
    float acc[8][4];
#pragma unroll
    for (int i = 0; i < 8; ++i)
#pragma unroll
        for (int j = 0; j < 4; ++j) acc[i][j] = 0.f;

    for (int k0 = 0; k0 < K; k0 += KC) {
        __syncthreads();
        // stage A tile: float4 coalesced loads, transposed scalar LDS writes
#pragma unroll
        for (int i = 0; i < NA; ++i) {
            int f = tid + i * TB;
            int row = f / F4R, fq = f % F4R;
            int gr = r0 + row;
            float4 v = make_float4(0.f, 0.f, 0.f, 0.f);
            if (gr < N_) {
                if (MODE == 0) {
                    int kg = k0 + fq * 4;
                    if (kg < 128) v = *(const float4*)&A[gr * 128 + kg];
                    else          v = *(const float4*)&te[gr * 16 + (kg - 128)];
                } else {
                    v = *(const float4*)&A[gr * K + k0 + fq * 4];
                }
            }
            As[fq * 4 + 0][row] = v.x;
            As[fq * 4 + 1][row] = v.y;
            As[fq * 4 + 2][row] = v.z;
            As[fq * 4 + 3][row] = v.w;
        }
        __syncthreads();
#pragma unroll
        for (int kk = 0; kk < KC; ++kk) {
            float4 a0 = *(const float4*)&As[kk][ty * 8];
            float4 a1 = *(const float4*)&As[kk][ty * 8 + 4];
            float av[8] = {a0.x, a0.y, a0.z, a0.w, a1.x, a1.y, a1.z, a1.w};
            float4 w = *(const float4*)&W[(k0 + kk) * M + tx * 4];   // L1/L2-resident
            float wv[4] = {w.x, w.y, w.z, w.w};
#pragma unroll
            for (int i = 0; i < 8; ++i)
#pragma unroll
                for (int j = 0; j < 4; ++j) acc[i][j] = fmaf(av[i], wv[j], acc[i][j]);
        }
    }

#pragma unroll
    for (int i = 0; i < 8; ++i) {
        int gr = r0 + ty * 8 + i;
        bool valid = gr < N_;
        if (MODE == 0) {
            if (valid) {
                float4 v;
                v.x = fmaxf(acc[i][0] + bias[tx * 4 + 0], 0.f);
                v.y = fmaxf(acc[i][1] + bias[tx * 4 + 1], 0.f);
                v.z = fmaxf(acc[i][2] + bias[tx * 4 + 2], 0.f);
                v.w = fmaxf(acc[i][3] + bias[tx * 4 + 3], 0.f);
                *(float4*)&Cout[gr * M + tx * 4] = v;
            }
        } else if (MODE == 1) {
            if (valid) {
                float4 v = make_float4(acc[i][0], acc[i][1], acc[i][2], acc[i][3]);
                *(float4*)&Cout[gr * M + tx * 4] = v;
            }
            float ps = 0.f, pd = 0.f;
#pragma unroll
            for (int q = 0; q < 4; ++q) {
                int c = tx * 4 + q;
                ps = fmaf(acc[i][q], asl[c], ps);
                pd = fmaf(acc[i][q], adl[c], pd);
            }
#pragma unroll
            for (int o = 1; o <= 4; o <<= 1) {
                ps += __shfl_xor(ps, o);
                pd += __shfl_xor(pd, o);
            }
            if (valid && (tx & 7) == 0) {
                int head = tx >> 3;
                al_s[gr * 4 + head] = ps;
                al_d[gr * 4 + head] = pd;
            }
        } else {
            float ps0 = 0.f, ps1 = 0.f;
#pragma unroll
            for (int q = 0; q < 4; ++q) {
                float hv = fmaxf(acc[i][q] + bias[tx * 4 + q], 0.f);
                int c = tx * 4 + q;
                ps0 = fmaf(hv, w2l[c * 2 + 0], ps0);
                ps1 = fmaf(hv, w2l[c * 2 + 1], ps1);
            }
#pragma unroll
            for (int o = 1; o <= 8; o <<= 1) {
                ps0 += __shfl_xor(ps0, o);
                ps1 += __shfl_xor(ps1, o);
            }
            if (valid && tx == 0) {
                *(float2*)&Cout[gr * 2] = make_float2(ps0 + b2[0], ps1 + b2[1]);
            }
        }
    }
}

// ---------------- GAT aggregation: 16-lane group per node, barrier-free ----------------
// v2: (a) HEAD FIX — broadcast all 4 head weights per edge and select by the
// RECEIVER's head (the old single-shfl broadcast delivered the SOURCE lane's
// head weight: wrong for 3/4 of receiving lanes; it hid under the threshold).
// (b) no max-subtraction (softmax is shift-invariant; logits are O(+-1) so exp
// is safe) — removes both per-chunk butterfly reductions from the critical
// chain; denominator = per-lane partials reduced once at the epilogue.
__global__ __launch_bounds__(256) void k_gat(const int* __restrict__ indptr, const int* __restrict__ srcs,
                                             const float* __restrict__ al_s, const float* __restrict__ al_d,
                                             const float* __restrict__ h2, const float* __restrict__ convb,
                                             const float* __restrict__ gamma, const float* __restrict__ beta,
                                             const float* __restrict__ mean, const float* __restrict__ var,
                                             const float* __restrict__ gate, float* __restrict__ hout) {
    int g = threadIdx.x >> 4, lg = threadIdx.x & 15;
    int n = blockIdx.x * 16 + g;
    if (n >= N_) return;
    int start = indptr[n], end = indptr[n + 1];
    int hl = lg >> 2;        // head owning my 8 channels
    int c0 = lg * 8;
    float gn = gate[n];
    float4 ad4 = *(const float4*)&al_d[n * 4];
    float adv[4] = {ad4.x, ad4.y, ad4.z, ad4.w};
    float Dp[4] = {0.f, 0.f, 0.f, 0.f};   // per-lane denominator partials
    float ac[8] = {0.f, 0.f, 0.f, 0.f, 0.f, 0.f, 0.f, 0.f};

    for (int p0 = start; p0 < end; p0 += 16) {
        int cs = end - p0;
        if (cs > 16) cs = 16;
        float w[4];
        int s = 0;
        if (lg < cs) {
            s = srcs[p0 + lg];
            float4 as4 = *(const float4*)&al_s[s * 4];
            float asv[4] = {as4.x, as4.y, as4.z, as4.w};
#pragma unroll
            for (int h = 0; h < 4; ++h) {
                float x = asv[h] + adv[h];
                x = x > 0.f ? x : 0.2f * x;
                w[h] = __expf(x);
                Dp[h] += w[h];
            }
        } else {
            w[0] = w[1] = w[2] = w[3] = 0.f;
        }
        int i = 0;
        for (; i + 1 < cs; i += 2) {
            float e0a = __shfl(w[0], i, 16), e0b = __shfl(w[1], i, 16);
            float e0c = __shfl(w[2], i, 16), e0d = __shfl(w[3], i, 16);
            float e1a = __shfl(w[0], i + 1, 16), e1b = __shfl(w[1], i + 1, 16);
            float e1c = __shfl(w[2], i + 1, 16), e1d = __shfl(w[3], i + 1, 16);
            float w0 = hl < 2 ? (hl == 0 ? e0a : e0b) : (hl == 2 ? e0c : e0d);
            float w1 = hl < 2 ? (hl == 0 ? e1a : e1b) : (hl == 2 ? e1c : e1d);
            int s0 = __shfl(s, i, 16);
            int s1 = __shfl(s, i + 1, 16);
            float4 h0a = *(const float4*)&h2[s0 * 128 + c0];
            float4 h0b = *(const float4*)&h2[s0 * 128 + c0 + 4];
            float4 h1a = *(const float4*)&h2[s1 * 128 + c0];
            float4 h1b = *(const float4*)&h2[s1 * 128 + c0 + 4];
            ac[0] = fmaf(w0, h0a.x, ac[0]); ac[1] = fmaf(w0, h0a.y, ac[1]);
            ac[2] = fmaf(w0, h0a.z, ac[2]); ac[3] = fmaf(w0, h0a.w, ac[3]);
            ac[4] = fmaf(w0, h0b.x, ac[4]); ac[5] = fmaf(w0, h0b.y, ac[5]);
            ac[6] = fmaf(w0, h0b.z, ac[6]); ac[7] = fmaf(w0, h0b.w, ac[7]);
            ac[0] = fmaf(w1, h1a.x, ac[0]); ac[1] = fmaf(w1, h1a.y, ac[1]);
            ac[2] = fmaf(w1, h1a.z, ac[2]); ac[3] = fmaf(w1, h1a.w, ac[3]);
            ac[4] = fmaf(w1, h1b.x, ac[4]); ac[5] = fmaf(w1, h1b.y, ac[5]);
            ac[6] = fmaf(w1, h1b.z, ac[6]); ac[7] = fmaf(w1, h1b.w, ac[7]);
        }
        if (i < cs) {
            float e0a = __shfl(w[0], i, 16), e0b = __shfl(w[1], i, 16);
            float e0c = __shfl(w[2], i, 16), e0d = __shfl(w[3], i, 16);
            float w0 = hl < 2 ? (hl == 0 ? e0a : e0b) : (hl == 2 ? e0c : e0d);
            int s0 = __shfl(s, i, 16);
            float4 h0a = *(const float4*)&h2[s0 * 128 + c0];
            float4 h0b = *(const float4*)&h2[s0 * 128 + c0 + 4];
            ac[0] = fmaf(w0, h0a.x, ac[0]); ac[1] = fmaf(w0, h0a.y, ac[1]);
            ac[2] = fmaf(w0, h0a.z, ac[2]); ac[3] = fmaf(w0, h0a.w, ac[3]);
            ac[4] = fmaf(w0, h0b.x, ac[4]); ac[5] = fmaf(w0, h0b.y, ac[5]);
            ac[6] = fmaf(w0, h0b.z, ac[6]); ac[7] = fmaf(w0, h0b.w, ac[7]);
        }
    }

    // epilogue: reduce denominator partials once, off the critical path
#pragma unroll
    for (int h = 0; h < 4; ++h) {
#pragma unroll
        for (int o = 8; o >= 1; o >>= 1) Dp[h] += __shfl_xor(Dp[h], o, 16);
    }
    float Dh = hl < 2 ? (hl == 0 ? Dp[0] : Dp[1]) : (hl == 2 ? Dp[2] : Dp[3]);
    float rd = 1.0f / (Dh + 1e-16f);
    float out8[8];
#pragma unroll
    for (int half = 0; half < 2; ++half) {
        int cb0 = c0 + half * 4;
        float4 cb = *(const float4*)&convb[cb0];
        float4 gm = *(const float4*)&gamma[cb0];
        float4 bt = *(const float4*)&beta[cb0];
        float4 mu = *(const float4*)&mean[cb0];
        float4 vr = *(const float4*)&var[cb0];
        float cbv[4] = {cb.x, cb.y, cb.z, cb.w};
        float gmv[4] = {gm.x, gm.y, gm.z, gm.w};
        float btv[4] = {bt.x, bt.y, bt.z, bt.w};
        float muv[4] = {mu.x, mu.y, mu.z, mu.w};
        float vrv[4] = {vr.x, vr.y, vr.z, vr.w};
#pragma unroll
        for (int q = 0; q < 4; ++q) {
            float val = ac[half * 4 + q] * rd + cbv[q];
            float sc = gmv[q] * rsqrtf(vrv[q] + 1e-5f);
            val = (val - muv[q]) * sc + btv[q];
            val = val > 0.f ? val : expm1f(val);
            out8[half * 4 + q] = val * gn;
        }
    }
    *(float4*)&hout[n * 128 + c0] = make_float4(out8[0], out8[1], out8[2], out8[3]);
    *(float4*)&hout[n * 128 + c0 + 4] = make_float4(out8[4], out8[5], out8[6], out8[7]);
}

extern "C" void kernel_launch(void* const* d_in, const int* in_sizes, int n_in,
                              void* d_out, int out_size, void* d_ws, size_t ws_size,
                              hipStream_t stream) {
    const float* x       = (const float*)d_in[0];
    const int*   ei      = (const int*)d_in[1];
    const int*   ts      = (const int*)d_in[2];
    const float* proj_w  = (const float*)d_in[3];
    const float* proj_b  = (const float*)d_in[4];
    const float* conv_w  = (const float*)d_in[5];
    const float* conv_b  = (const float*)d_in[6];
    const float* att_src = (const float*)d_in[7];
    const float* att_dst = (const float*)d_in[8];
    const float* bn_g    = (const float*)d_in[9];
    const float* bn_b    = (const float*)d_in[10];
    const float* bn_m    = (const float*)d_in[11];
    const float* bn_v    = (const float*)d_in[12];
    const float* gw1     = (const float*)d_in[13];
    const float* gb1     = (const float*)d_in[14];
    const float* gw2     = (const float*)d_in[15];
    const float* gb2     = (const float*)d_in[16];
    const float* hw1     = (const float*)d_in[17];
    const float* hb1     = (const float*)d_in[18];
    const float* hw2     = (const float*)d_in[19];
    const float* hb2     = (const float*)d_in[20];
    float* out = (float*)d_out;

    float* ws   = (float*)d_ws;
    float* h    = ws;
    float* h2   = h + (size_t)N_ * 128;
    float* te   = h2 + (size_t)N_ * 128;
    float* al_s = te + (size_t)N_ * 16;
    float* al_d = al_s + (size_t)N_ * 4;
    float* gate = al_d + (size_t)N_ * 4;
    int* indptr = (int*)(gate + N_);
    int* srcs   = indptr + (N_ + 1);
    int* count  = srcs + (N_ + E_);
    int* cursor = count + N_;
    int* bsum   = cursor + N_;
    int* bmin   = bsum + NBLK_;
    int* bmax   = bmin + NBLK_;
    int* minmax = bmax + NBLK_;

    k_prep<<<NBLK_, 256, 0, stream>>>(ts, te, count, bmin, bmax);
    k_count<<<(E_ + 255) / 256, 256, 0, stream>>>(ei, count);
    k_bsum<<<NBLK_, 256, 0, stream>>>(count, bsum);
    k_bscan<<<1, 512, 0, stream>>>(bsum, indptr, bmin, bmax, minmax);
    k_scan_c<<<NBLK_, 256, 0, stream>>>(count, bsum, indptr, srcs, cursor, ts, minmax,
                                        gw1, gb1, gw2, gb2, gate);
    k_scatter<<<(E_ + 255) / 256, 256, 0, stream>>>(ei, cursor, srcs);

    constexpr int GB = (N_ + 63) / 64;  // 1563 blocks (GR=64)
    k_gemm<144, 128, 16, 64, 0><<<GB, 256, 0, stream>>>(x, te, proj_w, proj_b, nullptr, nullptr,
                                                        nullptr, nullptr, h, nullptr, nullptr);
    for (int l = 0; l < 2; ++l) {
        k_gemm<128, 128, 16, 64, 1><<<GB, 256, 0, stream>>>(h, nullptr, conv_w + l * 128 * 128, nullptr,
                                                            att_src + l * 128, att_dst + l * 128,
                                                            nullptr, nullptr, h2, al_s, al_d);
        k_gat<<<(N_ + 15) / 16, 256, 0, stream>>>(indptr, srcs, al_s, al_d, h2, conv_b + l * 128,
                                                  bn_g + l * 128, bn_b + l * 128, bn_m + l * 128,
                                                  bn_v + l * 128, gate, h);
    }
    k_gemm<128, 64, 16, 64, 2><<<GB, 128, 0, stream>>>(h, nullptr, hw1, hb1, nullptr, nullptr,
                                                       hw2, hb2, out, nullptr, nullptr);
}

// Round 14
// 459.262 us; speedup vs baseline: 1.0944x; 1.0126x over previous
//
#include <hip/hip_runtime.h>
#include <cfloat>
#include <climits>
#include <cmath>

constexpr int N_ = 100000;
constexpr int E_ = 800000;
constexpr int NBLK_ = (N_ + 255) / 256;  // 391

// ---------------- time encoding + count init + per-block t min/max ----------------
__global__ __launch_bounds__(256) void k_prep(const int* __restrict__ ts, float* __restrict__ te,
                                              int* __restrict__ count, int* __restrict__ bmin,
                                              int* __restrict__ bmax) {
    const float FRQ[8] = {1.0f, 0.31622776601683794f, 0.1f, 0.031622776601683794f,
                          0.01f, 0.0031622776601683794f, 0.001f, 0.00031622776601683794f};
    int n = blockIdx.x * 256 + threadIdx.x;
    int tv_min = INT_MAX, tv_max = INT_MIN;
    if (n < N_) {
        int tv = ts[n];
        tv_min = tv; tv_max = tv;
        count[n] = 1;  // self loop
        float tf = (float)tv;
#pragma unroll
        for (int j = 0; j < 8; ++j) {
            float sv, cv;
            sincosf(tf * FRQ[j], &sv, &cv);
            te[n * 16 + j] = sv;
            te[n * 16 + 8 + j] = cv;
        }
    }
#pragma unroll
    for (int o = 32; o >= 1; o >>= 1) {
        tv_min = min(tv_min, __shfl_xor(tv_min, o));
        tv_max = max(tv_max, __shfl_xor(tv_max, o));
    }
    __shared__ int smn[4], smx[4];
    if ((threadIdx.x & 63) == 0) {
        smn[threadIdx.x >> 6] = tv_min;
        smx[threadIdx.x >> 6] = tv_max;
    }
    __syncthreads();
    if (threadIdx.x == 0) {
        bmin[blockIdx.x] = min(min(smn[0], smn[1]), min(smn[2], smn[3]));
        bmax[blockIdx.x] = max(max(smx[0], smx[1]), max(smx[2], smx[3]));
    }
}

__global__ __launch_bounds__(256) void k_count(const int* __restrict__ ei, int* __restrict__ count) {
    int e = blockIdx.x * 256 + threadIdx.x;
    if (e < E_) atomicAdd(&count[ei[E_ + e]], 1);
}

// ---- multi-block exclusive scan of count[N] ----
__global__ __launch_bounds__(256) void k_bsum(const int* __restrict__ count, int* __restrict__ bsum) {
    int i = blockIdx.x * 256 + threadIdx.x;
    int v = (i < N_) ? count[i] : 0;
#pragma unroll
    for (int o = 32; o >= 1; o >>= 1) v += __shfl_xor(v, o);
    __shared__ int wsum[4];
    if ((threadIdx.x & 63) == 0) wsum[threadIdx.x >> 6] = v;
    __syncthreads();
    if (threadIdx.x == 0) bsum[blockIdx.x] = wsum[0] + wsum[1] + wsum[2] + wsum[3];
}

__global__ __launch_bounds__(512) void k_bscan(int* __restrict__ bsum, int* __restrict__ indptr,
                                               const int* __restrict__ bmin, const int* __restrict__ bmax,
                                               int* __restrict__ minmax) {
    int t = threadIdx.x;
    int v = (t < NBLK_) ? bsum[t] : 0;
    __shared__ int sc[512];
    sc[t] = v;
    __syncthreads();
    for (int o = 1; o < 512; o <<= 1) {
        int u = (t >= o) ? sc[t - o] : 0;
        __syncthreads();
        sc[t] += u;
        __syncthreads();
    }
    if (t < NBLK_) bsum[t] = sc[t] - v;  // exclusive
    if (t == NBLK_ - 1) indptr[N_] = sc[t];
    // min/max reduce
    int mn = (t < NBLK_) ? bmin[t] : INT_MAX;
    int mx = (t < NBLK_) ? bmax[t] : INT_MIN;
#pragma unroll
    for (int o = 32; o >= 1; o >>= 1) {
        mn = min(mn, __shfl_xor(mn, o));
        mx = max(mx, __shfl_xor(mx, o));
    }
    __shared__ int rmn[8], rmx[8];
    if ((t & 63) == 0) { rmn[t >> 6] = mn; rmx[t >> 6] = mx; }
    __syncthreads();
    if (t == 0) {
        int a = INT_MAX, b = INT_MIN;
#pragma unroll
        for (int q = 0; q < 8; ++q) { a = min(a, rmn[q]); b = max(b, rmx[q]); }
        minmax[0] = a;
        minmax[1] = b;
    }
}

// intra-block scan + self-loop scatter + cursor init + (fused) gate MLP
__global__ __launch_bounds__(256) void k_scan_c(const int* __restrict__ count, const int* __restrict__ bsum,
                                                int* __restrict__ indptr, int* __restrict__ srcs,
                                                int* __restrict__ cursor, const int* __restrict__ ts,
                                                const int* __restrict__ minmax, const float* __restrict__ gw1,
                                                const float* __restrict__ gb1, const float* __restrict__ gw2,
                                                const float* __restrict__ gb2, float* __restrict__ gate) {
    int t = threadIdx.x;
    int i = blockIdx.x * 256 + t;
    int v = (i < N_) ? count[i] : 0;
    __shared__ int sc[256];
    sc[t] = v;
    __syncthreads();
    for (int o = 1; o < 256; o <<= 1) {
        int u = (t >= o) ? sc[t - o] : 0;
        __syncthreads();
        sc[t] += u;
        __syncthreads();
    }
    if (i < N_) {
        int off = bsum[blockIdx.x] + sc[t] - v;
        indptr[i] = off;
        srcs[off] = i;        // self loop first
        cursor[i] = off + 1;
        // gate
        float mn = (float)minmax[0], mx = (float)minmax[1];
        float age = ((float)ts[i] - mn) / fmaxf(mx - mn, 1.0f);
        float o2 = gb2[0];
#pragma unroll
        for (int j = 0; j < 16; ++j) {
            float hj = fmaxf(age * gw1[j] + gb1[j], 0.f);
            o2 += hj * gw2[j];
        }
        gate[i] = 1.f / (1.f + __expf(-o2));
    }
}

__global__ __launch_bounds__(256) void k_scatter(const int* __restrict__ ei, int* __restrict__ cursor,
                                                 int* __restrict__ srcs) {
    int e = blockIdx.x * 256 + threadIdx.x;
    if (e < E_) {
        int s = ei[e];
        int d = ei[E_ + e];
        int p = atomicAdd(&cursor[d], 1);
        srcs[p] = s;
    }
}

// ---------------- fused fp32 GEMM, GR-row x M-col tile, 8x4 per-thread ----------------
// SINGLE-WAVE blocks (TB=64, __launch_bounds__(64)): the compiler drops
// s_barrier entirely (barrier semantics degrade to in-wave s_waitcnt), so the
// staging<->compute sync never stalls other waves; 16-32 independent waves/CU
// hide each other's staging latency. GR=16 x M=128 per wave (head: 32x64).
// A tile in LDS (~1.3KB); W direct from global (8KB chunk, L1-resident,
// shared by all co-resident blocks). Inner loop & k-order identical to the
// proven round-12 kernel -> bit-identical output.
// MODE 0: proj (A=x concat te, +bias, relu)           -> Cout = h
// MODE 1: conv (raw) + attention-logit epilogue       -> Cout = h2, al_s, al_d
// MODE 2: head (+bias, relu, fused @w2+b2)            -> Cout = out (N,2)
template <int K, int M, int KC, int GR, int MODE>
__global__ __launch_bounds__((M / 4) * (GR / 8)) void k_gemm(const float* __restrict__ A, const float* __restrict__ te,
                                                             const float* __restrict__ W, const float* __restrict__ bias,
                                                             const float* __restrict__ asrc, const float* __restrict__ adst,
                                                             const float* __restrict__ w2, const float* __restrict__ b2,
                                                             float* __restrict__ Cout, float* __restrict__ al_s,
                                                             float* __restrict__ al_d) {
    constexpr int CTH = M / 4;             // col-threads
    constexpr int TB = CTH * (GR / 8);     // block threads
    constexpr int NA = (GR * KC / 4) / TB; // A float4 loads per thread
    constexpr int F4R = KC / 4;            // float4 slots per A row
    static_assert(K % KC == 0, "K%KC");
    static_assert(NA >= 1, "NA");
    __shared__ float As[KC][GR + 4];
    __shared__ float asl[128], adl[128];
    __shared__ float w2l[128];
    const int r0 = blockIdx.x * GR;
    const int tid = threadIdx.x;
    const int tx = tid % CTH, ty = tid / CTH;
    if (MODE == 1) {
        for (int i = tid; i < 128; i += TB) { asl[i] = asrc[i]; adl[i] = adst[i]; }
    }
    if (MODE == 2) {
        for (int i = tid; i < 128; i += TB) { w2l[i] = w2[i]; }
    }
    float acc[8][4];
#pragma unroll
    for (int i = 0; i < 8; ++i)
#pragma unroll
        for (int j = 0; j < 4; ++j) acc[i][j] = 0.f;

    for (int k0 = 0; k0 < K; k0 += KC) {
        __syncthreads();
        // stage A tile: float4 coalesced loads, transposed scalar LDS writes
#pragma unroll
        for (int i = 0; i < NA; ++i) {
            int f = tid + i * TB;
            int row = f / F4R, fq = f % F4R;
            int gr = r0 + row;
            float4 v = make_float4(0.f, 0.f, 0.f, 0.f);
            if (gr < N_) {
                if (MODE == 0) {
                    int kg = k0 + fq * 4;
                    if (kg < 128) v = *(const float4*)&A[gr * 128 + kg];
                    else          v = *(const float4*)&te[gr * 16 + (kg - 128)];
                } else {
                    v = *(const float4*)&A[gr * K + k0 + fq * 4];
                }
            }
            As[fq * 4 + 0][row] = v.x;
            As[fq * 4 + 1][row] = v.y;
            As[fq * 4 + 2][row] = v.z;
            As[fq * 4 + 3][row] = v.w;
        }
        __syncthreads();
#pragma unroll
        for (int kk = 0; kk < KC; ++kk) {
            float4 a0 = *(const float4*)&As[kk][ty * 8];
            float4 a1 = *(const float4*)&As[kk][ty * 8 + 4];
            float av[8] = {a0.x, a0.y, a0.z, a0.w, a1.x, a1.y, a1.z, a1.w};
            float4 w = *(const float4*)&W[(k0 + kk) * M + tx * 4];   // L1-resident
            float wv[4] = {w.x, w.y, w.z, w.w};
#pragma unroll
            for (int i = 0; i < 8; ++i)
#pragma unroll
                for (int j = 0; j < 4; ++j) acc[i][j] = fmaf(av[i], wv[j], acc[i][j]);
        }
    }

#pragma unroll
    for (int i = 0; i < 8; ++i) {
        int gr = r0 + ty * 8 + i;
        bool valid = gr < N_;
        if (MODE == 0) {
            if (valid) {
                float4 v;
                v.x = fmaxf(acc[i][0] + bias[tx * 4 + 0], 0.f);
                v.y = fmaxf(acc[i][1] + bias[tx * 4 + 1], 0.f);
                v.z = fmaxf(acc[i][2] + bias[tx * 4 + 2], 0.f);
                v.w = fmaxf(acc[i][3] + bias[tx * 4 + 3], 0.f);
                *(float4*)&Cout[gr * M + tx * 4] = v;
            }
        } else if (MODE == 1) {
            if (valid) {
                float4 v = make_float4(acc[i][0], acc[i][1], acc[i][2], acc[i][3]);
                *(float4*)&Cout[gr * M + tx * 4] = v;
            }
            float ps = 0.f, pd = 0.f;
#pragma unroll
            for (int q = 0; q < 4; ++q) {
                int c = tx * 4 + q;
                ps = fmaf(acc[i][q], asl[c], ps);
                pd = fmaf(acc[i][q], adl[c], pd);
            }
#pragma unroll
            for (int o = 1; o <= 4; o <<= 1) {
                ps += __shfl_xor(ps, o);
                pd += __shfl_xor(pd, o);
            }
            if (valid && (tx & 7) == 0) {
                int head = tx >> 3;
                al_s[gr * 4 + head] = ps;
                al_d[gr * 4 + head] = pd;
            }
        } else {
            float ps0 = 0.f, ps1 = 0.f;
#pragma unroll
            for (int q = 0; q < 4; ++q) {
                float hv = fmaxf(acc[i][q] + bias[tx * 4 + q], 0.f);
                int c = tx * 4 + q;
                ps0 = fmaf(hv, w2l[c * 2 + 0], ps0);
                ps1 = fmaf(hv, w2l[c * 2 + 1], ps1);
            }
#pragma unroll
            for (int o = 1; o <= 8; o <<= 1) {
                ps0 += __shfl_xor(ps0, o);
                ps1 += __shfl_xor(ps1, o);
            }
            if (valid && tx == 0) {
                *(float2*)&Cout[gr * 2] = make_float2(ps0 + b2[0], ps1 + b2[1]);
            }
        }
    }
}

// ---------------- GAT aggregation: 16-lane group per node, barrier-free ----------------
// Proven round-13 config: head-correct 4-shuffle broadcast, no max-subtraction,
// epilogue denominator reduce. VGPR 32, occ ~72%.
__global__ __launch_bounds__(256) void k_gat(const int* __restrict__ indptr, const int* __restrict__ srcs,
                                             const float* __restrict__ al_s, const float* __restrict__ al_d,
                                             const float* __restrict__ h2, const float* __restrict__ convb,
                                             const float* __restrict__ gamma, const float* __restrict__ beta,
                                             const float* __restrict__ mean, const float* __restrict__ var,
                                             const float* __restrict__ gate, float* __restrict__ hout) {
    int g = threadIdx.x >> 4, lg = threadIdx.x & 15;
    int n = blockIdx.x * 16 + g;
    if (n >= N_) return;
    int start = indptr[n], end = indptr[n + 1];
    int hl = lg >> 2;        // head owning my 8 channels
    int c0 = lg * 8;
    float gn = gate[n];
    float4 ad4 = *(const float4*)&al_d[n * 4];
    float adv[4] = {ad4.x, ad4.y, ad4.z, ad4.w};
    float Dp[4] = {0.f, 0.f, 0.f, 0.f};   // per-lane denominator partials
    float ac[8] = {0.f, 0.f, 0.f, 0.f, 0.f, 0.f, 0.f, 0.f};

    for (int p0 = start; p0 < end; p0 += 16) {
        int cs = end - p0;
        if (cs > 16) cs = 16;
        float w[4];
        int s = 0;
        if (lg < cs) {
            s = srcs[p0 + lg];
            float4 as4 = *(const float4*)&al_s[s * 4];
            float asv[4] = {as4.x, as4.y, as4.z, as4.w};
#pragma unroll
            for (int h = 0; h < 4; ++h) {
                float x = asv[h] + adv[h];
                x = x > 0.f ? x : 0.2f * x;
                w[h] = __expf(x);
                Dp[h] += w[h];
            }
        } else {
            w[0] = w[1] = w[2] = w[3] = 0.f;
        }
        int i = 0;
        for (; i + 1 < cs; i += 2) {
            float e0a = __shfl(w[0], i, 16), e0b = __shfl(w[1], i, 16);
            float e0c = __shfl(w[2], i, 16), e0d = __shfl(w[3], i, 16);
            float e1a = __shfl(w[0], i + 1, 16), e1b = __shfl(w[1], i + 1, 16);
            float e1c = __shfl(w[2], i + 1, 16), e1d = __shfl(w[3], i + 1, 16);
            float w0 = hl < 2 ? (hl == 0 ? e0a : e0b) : (hl == 2 ? e0c : e0d);
            float w1 = hl < 2 ? (hl == 0 ? e1a : e1b) : (hl == 2 ? e1c : e1d);
            int s0 = __shfl(s, i, 16);
            int s1 = __shfl(s, i + 1, 16);
            float4 h0a = *(const float4*)&h2[s0 * 128 + c0];
            float4 h0b = *(const float4*)&h2[s0 * 128 + c0 + 4];
            float4 h1a = *(const float4*)&h2[s1 * 128 + c0];
            float4 h1b = *(const float4*)&h2[s1 * 128 + c0 + 4];
            ac[0] = fmaf(w0, h0a.x, ac[0]); ac[1] = fmaf(w0, h0a.y, ac[1]);
            ac[2] = fmaf(w0, h0a.z, ac[2]); ac[3] = fmaf(w0, h0a.w, ac[3]);
            ac[4] = fmaf(w0, h0b.x, ac[4]); ac[5] = fmaf(w0, h0b.y, ac[5]);
            ac[6] = fmaf(w0, h0b.z, ac[6]); ac[7] = fmaf(w0, h0b.w, ac[7]);
            ac[0] = fmaf(w1, h1a.x, ac[0]); ac[1] = fmaf(w1, h1a.y, ac[1]);
            ac[2] = fmaf(w1, h1a.z, ac[2]); ac[3] = fmaf(w1, h1a.w, ac[3]);
            ac[4] = fmaf(w1, h1b.x, ac[4]); ac[5] = fmaf(w1, h1b.y, ac[5]);
            ac[6] = fmaf(w1, h1b.z, ac[6]); ac[7] = fmaf(w1, h1b.w, ac[7]);
        }
        if (i < cs) {
            float e0a = __shfl(w[0], i, 16), e0b = __shfl(w[1], i, 16);
            float e0c = __shfl(w[2], i, 16), e0d = __shfl(w[3], i, 16);
            float w0 = hl < 2 ? (hl == 0 ? e0a : e0b) : (hl == 2 ? e0c : e0d);
            int s0 = __shfl(s, i, 16);
            float4 h0a = *(const float4*)&h2[s0 * 128 + c0];
            float4 h0b = *(const float4*)&h2[s0 * 128 + c0 + 4];
            ac[0] = fmaf(w0, h0a.x, ac[0]); ac[1] = fmaf(w0, h0a.y, ac[1]);
            ac[2] = fmaf(w0, h0a.z, ac[2]); ac[3] = fmaf(w0, h0a.w, ac[3]);
            ac[4] = fmaf(w0, h0b.x, ac[4]); ac[5] = fmaf(w0, h0b.y, ac[5]);
            ac[6] = fmaf(w0, h0b.z, ac[6]); ac[7] = fmaf(w0, h0b.w, ac[7]);
        }
    }

    // epilogue: reduce denominator partials once, off the critical path
#pragma unroll
    for (int h = 0; h < 4; ++h) {
#pragma unroll
        for (int o = 8; o >= 1; o >>= 1) Dp[h] += __shfl_xor(Dp[h], o, 16);
    }
    float Dh = hl < 2 ? (hl == 0 ? Dp[0] : Dp[1]) : (hl == 2 ? Dp[2] : Dp[3]);
    float rd = 1.0f / (Dh + 1e-16f);
    float out8[8];
#pragma unroll
    for (int half = 0; half < 2; ++half) {
        int cb0 = c0 + half * 4;
        float4 cb = *(const float4*)&convb[cb0];
        float4 gm = *(const float4*)&gamma[cb0];
        float4 bt = *(const float4*)&beta[cb0];
        float4 mu = *(const float4*)&mean[cb0];
        float4 vr = *(const float4*)&var[cb0];
        float cbv[4] = {cb.x, cb.y, cb.z, cb.w};
        float gmv[4] = {gm.x, gm.y, gm.z, gm.w};
        float btv[4] = {bt.x, bt.y, bt.z, bt.w};
        float muv[4] = {mu.x, mu.y, mu.z, mu.w};
        float vrv[4] = {vr.x, vr.y, vr.z, vr.w};
#pragma unroll
        for (int q = 0; q < 4; ++q) {
            float val = ac[half * 4 + q] * rd + cbv[q];
            float sc = gmv[q] * rsqrtf(vrv[q] + 1e-5f);
            val = (val - muv[q]) * sc + btv[q];
            val = val > 0.f ? val : expm1f(val);
            out8[half * 4 + q] = val * gn;
        }
    }
    *(float4*)&hout[n * 128 + c0] = make_float4(out8[0], out8[1], out8[2], out8[3]);
    *(float4*)&hout[n * 128 + c0 + 4] = make_float4(out8[4], out8[5], out8[6], out8[7]);
}

extern "C" void kernel_launch(void* const* d_in, const int* in_sizes, int n_in,
                              void* d_out, int out_size, void* d_ws, size_t ws_size,
                              hipStream_t stream) {
    const float* x       = (const float*)d_in[0];
    const int*   ei      = (const int*)d_in[1];
    const int*   ts      = (const int*)d_in[2];
    const float* proj_w  = (const float*)d_in[3];
    const float* proj_b  = (const float*)d_in[4];
    const float* conv_w  = (const float*)d_in[5];
    const float* conv_b  = (const float*)d_in[6];
    const float* att_src = (const float*)d_in[7];
    const float* att_dst = (const float*)d_in[8];
    const float* bn_g    = (const float*)d_in[9];
    const float* bn_b    = (const float*)d_in[10];
    const float* bn_m    = (const float*)d_in[11];
    const float* bn_v    = (const float*)d_in[12];
    const float* gw1     = (const float*)d_in[13];
    const float* gb1     = (const float*)d_in[14];
    const float* gw2     = (const float*)d_in[15];
    const float* gb2     = (const float*)d_in[16];
    const float* hw1     = (const float*)d_in[17];
    const float* hb1     = (const float*)d_in[18];
    const float* hw2     = (const float*)d_in[19];
    const float* hb2     = (const float*)d_in[20];
    float* out = (float*)d_out;

    float* ws   = (float*)d_ws;
    float* h    = ws;
    float* h2   = h + (size_t)N_ * 128;
    float* te   = h2 + (size_t)N_ * 128;
    float* al_s = te + (size_t)N_ * 16;
    float* al_d = al_s + (size_t)N_ * 4;
    float* gate = al_d + (size_t)N_ * 4;
    int* indptr = (int*)(gate + N_);
    int* srcs   = indptr + (N_ + 1);
    int* count  = srcs + (N_ + E_);
    int* cursor = count + N_;
    int* bsum   = cursor + N_;
    int* bmin   = bsum + NBLK_;
    int* bmax   = bmin + NBLK_;
    int* minmax = bmax + NBLK_;

    k_prep<<<NBLK_, 256, 0, stream>>>(ts, te, count, bmin, bmax);
    k_count<<<(E_ + 255) / 256, 256, 0, stream>>>(ei, count);
    k_bsum<<<NBLK_, 256, 0, stream>>>(count, bsum);
    k_bscan<<<1, 512, 0, stream>>>(bsum, indptr, bmin, bmax, minmax);
    k_scan_c<<<NBLK_, 256, 0, stream>>>(count, bsum, indptr, srcs, cursor, ts, minmax,
                                        gw1, gb1, gw2, gb2, gate);
    k_scatter<<<(E_ + 255) / 256, 256, 0, stream>>>(ei, cursor, srcs);

    constexpr int GB16 = (N_ + 15) / 16;  // 6250 single-wave blocks (GR=16)
    constexpr int GB32 = (N_ + 31) / 32;  // 3125 single-wave blocks (GR=32)
    k_gemm<144, 128, 16, 16, 0><<<GB16, 64, 0, stream>>>(x, te, proj_w, proj_b, nullptr, nullptr,
                                                         nullptr, nullptr, h, nullptr, nullptr);
    for (int l = 0; l < 2; ++l) {
        k_gemm<128, 128, 16, 16, 1><<<GB16, 64, 0, stream>>>(h, nullptr, conv_w + l * 128 * 128, nullptr,
                                                             att_src + l * 128, att_dst + l * 128,
                                                             nullptr, nullptr, h2, al_s, al_d);
        k_gat<<<(N_ + 15) / 16, 256, 0, stream>>>(indptr, srcs, al_s, al_d, h2, conv_b + l * 128,
                                                  bn_g + l * 128, bn_b + l * 128, bn_m + l * 128,
                                                  bn_v + l * 128, gate, h);
    }
    k_gemm<128, 64, 16, 32, 2><<<GB32, 64, 0, stream>>>(h, nullptr, hw1, hb1, nullptr, nullptr,
                                                        hw2, hb2, out, nullptr, nullptr);
}